// Round 8
// baseline (527.651 us; speedup 1.0000x reference)
//
#include <hip/hip_runtime.h>
#include <hip/hip_bf16.h>

// Problem dims (fixed)
#define B_ 2
#define L_ 2048
#define D_ 1024
#define E_ 2048
#define N_ 16
#define DR_ 64
#define DC_ 4
#define M_ (B_*L_)   // 4096 rows
#define SSEG 64      // scan segments
#define LSEG 32      // timesteps per segment
#define KS_ 8        // split-K factor for C96 GEMM

typedef __attribute__((ext_vector_type(8))) short bf16x8;
typedef __attribute__((ext_vector_type(4))) float f32x4;

__device__ __forceinline__ ushort f2bf(float x){
    union { float f; unsigned u; } v; v.f = x;
    unsigned r = v.u + 0x7FFFu + ((v.u >> 16) & 1u);
    return (ushort)(r >> 16);
}
__device__ __forceinline__ float bf2f(ushort u){
    union { unsigned u; float f; } v; v.u = ((unsigned)u) << 16;
    return v.f;
}

// async global->LDS, 16B per lane. LDS dest = wave-uniform base + lane*16.
__device__ __forceinline__ void gld16(const void* g, void* l){
    __builtin_amdgcn_global_load_lds(
        (const __attribute__((address_space(1))) unsigned int*)g,
        (__attribute__((address_space(3))) unsigned int*)l,
        16, 0, 0);
}

// ---------------- convert f32 -> bf16 (vec4) ----------------
__global__ void cvt4_k(const float* __restrict__ in, ushort* __restrict__ out, int n4){
    int i = blockIdx.x * 256 + threadIdx.x;
    if (i < n4){
        float4 v = ((const float4*)in)[i];
        ushort4 o;
        o.x = f2bf(v.x); o.y = f2bf(v.y); o.z = f2bf(v.z); o.w = f2bf(v.w);
        ((ushort4*)out)[i] = o;
    }
}

__global__ void zero16_k(ushort* __restrict__ p, int n){
    int i = blockIdx.x * 256 + threadIdx.x;
    if (i < n) p[i] = 0;
}

// ---------------- RMSNorm -> bf16 ----------------
__global__ __launch_bounds__(256) void rmsnorm_k(const float* __restrict__ resid,
                                                 const float* __restrict__ norm_w,
                                                 ushort* __restrict__ xn){
    int row = blockIdx.x;
    const float4* r = (const float4*)(resid + (size_t)row * D_);
    float4 v = r[threadIdx.x];
    float ss = v.x*v.x + v.y*v.y + v.z*v.z + v.w*v.w;
    for (int m = 32; m; m >>= 1) ss += __shfl_xor(ss, m);
    __shared__ float sred[4];
    if ((threadIdx.x & 63) == 0) sred[threadIdx.x >> 6] = ss;
    __syncthreads();
    float tot = sred[0] + sred[1] + sred[2] + sred[3];
    float scale = rsqrtf(tot / (float)D_ + 1e-5f);
    const float4* wv = (const float4*)norm_w;
    float4 w = wv[threadIdx.x];
    ushort4 o;
    o.x = f2bf(v.x * scale * w.x);
    o.y = f2bf(v.y * scale * w.y);
    o.z = f2bf(v.z * scale * w.z);
    o.w = f2bf(v.w * scale * w.w);
    ((ushort4*)(xn + (size_t)row * D_))[threadIdx.x] = o;
}

// ---------------- GEMM: C[M,N] = A[M,K] * B[N,K]^T, bf16 in, f32 acc ----------------
// global_load_lds width-16 staging into LINEAR LDS [128][64] (m97 structure).
// EPI: 1 = bf16 store, 3 = acc + aux[idx] f32 store
#define BM 128
#define BN 128
#define BK 64

template<int EPI>
__global__ __launch_bounds__(256)
void gemm_bt(const ushort* __restrict__ A, const ushort* __restrict__ Bm,
             void* __restrict__ Cp, const float* __restrict__ aux,
             int M, int N, int K, int lda, int ldb, int ldc){
    __shared__ __align__(16) ushort As[BM * BK];
    __shared__ __align__(16) ushort Bs[BN * BK];
    const int col0 = blockIdx.x * BN;
    const int row0 = blockIdx.y * BM;
    const int tid = threadIdx.x;
    const int lane = tid & 63;
    const int wid = tid >> 6;
    const int wm = wid >> 1, wn = wid & 1;   // 2x2 waves of 64x64
    f32x4 acc[4][4] = {};

    const int l8 = lane >> 3;        // row within 8-row group
    const int c8 = (lane & 7) * 8;   // col (elements)

    for (int k0 = 0; k0 < K; k0 += BK){
        #pragma unroll
        for (int i = 0; i < 4; ++i){
            const int R0 = wid * 32 + i * 8;   // 8 rows per instr
            gld16(A + (size_t)(row0 + R0 + l8) * lda + k0 + c8, As + R0 * BK);
            gld16(Bm + (size_t)(col0 + R0 + l8) * ldb + k0 + c8, Bs + R0 * BK);
        }
        __syncthreads();   // drains vmcnt before barrier
        #pragma unroll
        for (int kk = 0; kk < 2; ++kk){
            bf16x8 af[4], bfr[4];
            const int krow = lane & 15;
            const int kcol = kk * 32 + (lane >> 4) * 8;
            #pragma unroll
            for (int mi = 0; mi < 4; ++mi)
                af[mi] = *(const bf16x8*)(As + (wm*64 + mi*16 + krow) * BK + kcol);
            #pragma unroll
            for (int ni = 0; ni < 4; ++ni)
                bfr[ni] = *(const bf16x8*)(Bs + (wn*64 + ni*16 + krow) * BK + kcol);
            #pragma unroll
            for (int mi = 0; mi < 4; ++mi)
                #pragma unroll
                for (int ni = 0; ni < 4; ++ni)
                    acc[mi][ni] = __builtin_amdgcn_mfma_f32_16x16x32_bf16(af[mi], bfr[ni], acc[mi][ni], 0, 0, 0);
        }
        __syncthreads();
    }

    #pragma unroll
    for (int mi = 0; mi < 4; ++mi)
        #pragma unroll
        for (int ni = 0; ni < 4; ++ni)
            #pragma unroll
            for (int j = 0; j < 4; ++j){
                int r = row0 + wm*64 + mi*16 + (lane >> 4) * 4 + j;
                int c = col0 + wn*64 + ni*16 + (lane & 15);
                size_t idx = (size_t)r * ldc + c;
                float v = acc[mi][ni][j];
                if (EPI == 1){
                    ((ushort*)Cp)[idx] = f2bf(v);
                } else {
                    ((float*)Cp)[idx] = v + aux[idx];
                }
            }
}

// ---------------- C96 GEMM, split-K: part[ks][4096][128] f32 partials ----------------
__global__ __launch_bounds__(256)
void gemm_c96_sk(const ushort* __restrict__ A, const ushort* __restrict__ Bm,
                 float* __restrict__ part){
    __shared__ __align__(16) ushort As[BM * BK];
    __shared__ __align__(16) ushort Bs[BN * BK];
    const int ks = blockIdx.x;
    const int row0 = blockIdx.y * BM;
    const int tid = threadIdx.x;
    const int lane = tid & 63;
    const int wid = tid >> 6;
    const int wm = wid >> 1, wn = wid & 1;
    f32x4 acc[4][4] = {};
    const int l8 = lane >> 3;
    const int c8 = (lane & 7) * 8;

    for (int k0 = ks * (E_ / KS_); k0 < (ks + 1) * (E_ / KS_); k0 += BK){
        #pragma unroll
        for (int i = 0; i < 4; ++i){
            const int R0 = wid * 32 + i * 8;
            gld16(A + (size_t)(row0 + R0 + l8) * E_ + k0 + c8, As + R0 * BK);
            gld16(Bm + (size_t)(R0 + l8) * E_ + k0 + c8, Bs + R0 * BK);
        }
        __syncthreads();
        #pragma unroll
        for (int kk = 0; kk < 2; ++kk){
            bf16x8 af[4], bfr[4];
            const int krow = lane & 15;
            const int kcol = kk * 32 + (lane >> 4) * 8;
            #pragma unroll
            for (int mi = 0; mi < 4; ++mi)
                af[mi] = *(const bf16x8*)(As + (wm*64 + mi*16 + krow) * BK + kcol);
            #pragma unroll
            for (int ni = 0; ni < 4; ++ni)
                bfr[ni] = *(const bf16x8*)(Bs + (wn*64 + ni*16 + krow) * BK + kcol);
            #pragma unroll
            for (int mi = 0; mi < 4; ++mi)
                #pragma unroll
                for (int ni = 0; ni < 4; ++ni)
                    acc[mi][ni] = __builtin_amdgcn_mfma_f32_16x16x32_bf16(af[mi], bfr[ni], acc[mi][ni], 0, 0, 0);
        }
        __syncthreads();
    }
    float* dst = part + (size_t)ks * M_ * 128;
    #pragma unroll
    for (int mi = 0; mi < 4; ++mi)
        #pragma unroll
        for (int ni = 0; ni < 4; ++ni)
            #pragma unroll
            for (int j = 0; j < 4; ++j){
                int r = row0 + wm*64 + mi*16 + (lane >> 4) * 4 + j;
                int c = wn*64 + ni*16 + (lane & 15);
                dst[(size_t)r * 128 + c] = acc[mi][ni][j];
            }
}

// reduce split-K partials -> C96 bf16; also emit cols 64..95 as f32 (BCf) for the scan
__global__ __launch_bounds__(256) void c96_reduce_k(const float* __restrict__ part,
                                                    ushort* __restrict__ C96,
                                                    float* __restrict__ BCf){
    int i4 = blockIdx.x * 256 + threadIdx.x;     // over M_*128/4
    float4 a = *(const float4*)(part + (size_t)i4 * 4);
    #pragma unroll
    for (int k = 1; k < KS_; ++k){
        float4 b = *(const float4*)(part + (size_t)k * M_ * 128 + (size_t)i4 * 4);
        a.x += b.x; a.y += b.y; a.z += b.z; a.w += b.w;
    }
    ushort4 o;
    o.x = f2bf(a.x); o.y = f2bf(a.y); o.z = f2bf(a.z); o.w = f2bf(a.w);
    *(ushort4*)(C96 + (size_t)i4 * 4) = o;
    int idx = i4 * 4;
    int col = idx & 127;
    int row = idx >> 7;
    if (col >= 64 && col < 96)
        *(float4*)(BCf + (size_t)row * 32 + (col - 64)) = a;
}

// ---------------- causal depthwise conv1d + silu (vec4 along e) ----------------
__global__ __launch_bounds__(256) void conv_silu_k(const ushort* __restrict__ xpre,
                                                   const float* __restrict__ conv_w,
                                                   const float* __restrict__ conv_b,
                                                   float* __restrict__ xf,
                                                   ushort* __restrict__ xb){
    int i4 = blockIdx.x * 256 + threadIdx.x;
    if (i4 >= M_ * E_ / 4) return;
    int idx = i4 * 4;
    int e = idx & (E_ - 1);
    int bl = idx >> 11;
    int t = bl & (L_ - 1);
    float acc[4];
    #pragma unroll
    for (int j = 0; j < 4; ++j) acc[j] = conv_b[e + j];
    #pragma unroll
    for (int k = 0; k < 4; ++k){
        int dt = 3 - k;
        if (t >= dt){
            ushort4 xv = *(const ushort4*)(xpre + idx - dt * E_);
            acc[0] += bf2f(xv.x) * conv_w[(e+0)*4 + k];
            acc[1] += bf2f(xv.y) * conv_w[(e+1)*4 + k];
            acc[2] += bf2f(xv.z) * conv_w[(e+2)*4 + k];
            acc[3] += bf2f(xv.w) * conv_w[(e+3)*4 + k];
        }
    }
    float4 so; ushort4 sb;
    float* sp = (float*)&so;
    #pragma unroll
    for (int j = 0; j < 4; ++j){
        float s = acc[j] / (1.f + __expf(-acc[j]));
        sp[j] = s;
    }
    sb.x = f2bf(so.x); sb.y = f2bf(so.y); sb.z = f2bf(so.z); sb.w = f2bf(so.w);
    *(float4*)(xf + idx) = so;
    *(ushort4*)(xb + idx) = sb;
}

// ---------------- n-in-register chunk-parallel selective scan ----------------
// Thread owns one e, all 16 n-states in registers; wave = one 32-t segment x 64 e.
// Block = 4 waves = 4 consecutive segments; zero block barriers (per-wave staging).
// delta fused via MFMA; redistribution t-order<->e-order via per-wave LDS bounce
// (ds_write_b128 x4 + ds_read_b128 x4 per 16-t tile) -- NOT shuffle-rotation
// (rq/dts arrays cost ~32 persistent VGPRs and spilled at the 128-reg cap, r6/r7).
// PASS2: y output fused with gating -> y2 bf16.

#define DST 20   // sdel row stride (floats): 80B, 16B-aligned, disjoint bank quads

template<int PASS2>
__global__ __launch_bounds__(256, 2)
void scan_k(const float* __restrict__ xf, const ushort* __restrict__ C96,
            const float* __restrict__ BCf, const ushort* __restrict__ wd2b,
            const float* __restrict__ wd2_bias, const float* __restrict__ A_log,
            const float* __restrict__ carr,
            float* __restrict__ F, float* __restrict__ segdt,
            const ushort* __restrict__ skipb, const float* __restrict__ W_D,
            ushort* __restrict__ y2)
{
    const int tid = threadIdx.x;
    const int w = tid >> 6, lane = tid & 63;
    const int q = lane >> 4, c = lane & 15;
    const int e0 = blockIdx.x * 64;
    const int g = blockIdx.y;          // seg-group: segs 4g..4g+3, t-window g*128..+128
    const int b = blockIdx.z;
    const int e = e0 + lane;
    const int seg = g * 4 + w;
    const size_t grow0 = (size_t)b * L_ + (size_t)g * 128;   // global row of window start

    __shared__ __align__(16) ushort sxr[128 * 64];   // [r][64]bf16; 16B-chunk XOR-swizzled
    __shared__ __align__(16) float  sBC[128 * 32];   // [r][B n0..15 | C n0..15] f32 linear
    __shared__ __align__(16) float  sdel[4][64 * DST + 4]; // per-wave delta bounce tile

    // stage this wave's 32 rows (xr swizzled so MFMA b128 reads are conflict-free)
    #pragma unroll
    for (int k2 = 0; k2 < 4; ++k2){
        int R0 = w * 32 + k2 * 8;
        int r = R0 + (lane >> 3);
        int cc = (lane & 7) ^ (r & 7);
        gld16(C96 + (grow0 + r) * 128 + cc * 8, sxr + R0 * 64);
        gld16(BCf + (grow0 + r) * 32 + (lane & 7) * 4, sBC + R0 * 32);
    }
    asm volatile("s_waitcnt vmcnt(0)" ::: "memory");
    __builtin_amdgcn_sched_barrier(0);

    float Aen[16];
    {
        const float4* al = (const float4*)(A_log + (size_t)e * N_);
        #pragma unroll
        for (int g4 = 0; g4 < 4; ++g4){
            float4 v = al[g4];
            Aen[g4*4+0] = -__expf(v.x); Aen[g4*4+1] = -__expf(v.y);
            Aen[g4*4+2] = -__expf(v.z); Aen[g4*4+3] = -__expf(v.w);
        }
    }
    float h[16];
    if (PASS2){
        const float4* cp = (const float4*)(carr + ((size_t)(b * SSEG + seg) * E_ + e) * N_);
        #pragma unroll
        for (int g4 = 0; g4 < 4; ++g4){
            float4 v = cp[g4];
            h[g4*4+0] = v.x; h[g4*4+1] = v.y; h[g4*4+2] = v.z; h[g4*4+3] = v.w;
        }
    } else {
        #pragma unroll
        for (int n = 0; n < 16; ++n) h[n] = 0.f;
    }

    bf16x8 wfrag[4][2];
    #pragma unroll
    for (int m = 0; m < 4; ++m)
        #pragma unroll
        for (int kk = 0; kk < 2; ++kk)
            wfrag[m][kk] = *(const bf16x8*)(wd2b + (size_t)(e0 + m*16 + c) * DR_ + kk*32 + q*8);

    // bias for the 4 e's this lane PRODUCES delta for (e0 + m*16 + c)
    float bias4[4];
    #pragma unroll
    for (int m = 0; m < 4; ++m) bias4[m] = wd2_bias[e0 + m*16 + c];

    const float wde = PASS2 ? W_D[e] : 0.f;
    float sdt = 0.f;
    float* sdw = &sdel[w][0];

    #pragma unroll
    for (int tt = 0; tt < 2; ++tt){
        const int tb = w * 32 + tt * 16;   // window row of tile base
        // --- fused delta: 8 MFMAs, D: lane holds e_in=c (block m), t_in=q*4+j
        f32x4 d0 = {}, d1 = {}, d2 = {}, d3 = {};
        #pragma unroll
        for (int kk = 0; kk < 2; ++kk){
            int r = tb + c;
            int chunk = kk * 4 + q;
            bf16x8 af = *(const bf16x8*)(sxr + r * 64 + ((chunk ^ (r & 7)) << 3));
            d0 = __builtin_amdgcn_mfma_f32_16x16x32_bf16(af, wfrag[0][kk], d0, 0, 0, 0);
            d1 = __builtin_amdgcn_mfma_f32_16x16x32_bf16(af, wfrag[1][kk], d1, 0, 0, 0);
            d2 = __builtin_amdgcn_mfma_f32_16x16x32_bf16(af, wfrag[2][kk], d2, 0, 0, 0);
            d3 = __builtin_amdgcn_mfma_f32_16x16x32_bf16(af, wfrag[3][kk], d3, 0, 0, 0);
        }
        // --- softplus at producer, bounce through per-wave LDS tile [e-local][t-local]
        {
            float4 o;
            o.x = d0[0] + bias4[0]; o.y = d0[1] + bias4[0];
            o.z = d0[2] + bias4[0]; o.w = d0[3] + bias4[0];
            o.x = (o.x > 20.f) ? o.x : log1pf(__expf(o.x));
            o.y = (o.y > 20.f) ? o.y : log1pf(__expf(o.y));
            o.z = (o.z > 20.f) ? o.z : log1pf(__expf(o.z));
            o.w = (o.w > 20.f) ? o.w : log1pf(__expf(o.w));
            *(float4*)(sdw + (0*16 + c) * DST + q * 4) = o;
            o.x = d1[0] + bias4[1]; o.y = d1[1] + bias4[1];
            o.z = d1[2] + bias4[1]; o.w = d1[3] + bias4[1];
            o.x = (o.x > 20.f) ? o.x : log1pf(__expf(o.x));
            o.y = (o.y > 20.f) ? o.y : log1pf(__expf(o.y));
            o.z = (o.z > 20.f) ? o.z : log1pf(__expf(o.z));
            o.w = (o.w > 20.f) ? o.w : log1pf(__expf(o.w));
            *(float4*)(sdw + (1*16 + c) * DST + q * 4) = o;
            o.x = d2[0] + bias4[2]; o.y = d2[1] + bias4[2];
            o.z = d2[2] + bias4[2]; o.w = d2[3] + bias4[2];
            o.x = (o.x > 20.f) ? o.x : log1pf(__expf(o.x));
            o.y = (o.y > 20.f) ? o.y : log1pf(__expf(o.y));
            o.z = (o.z > 20.f) ? o.z : log1pf(__expf(o.z));
            o.w = (o.w > 20.f) ? o.w : log1pf(__expf(o.w));
            *(float4*)(sdw + (2*16 + c) * DST + q * 4) = o;
            o.x = d3[0] + bias4[3]; o.y = d3[1] + bias4[3];
            o.z = d3[2] + bias4[3]; o.w = d3[3] + bias4[3];
            o.x = (o.x > 20.f) ? o.x : log1pf(__expf(o.x));
            o.y = (o.y > 20.f) ? o.y : log1pf(__expf(o.y));
            o.z = (o.z > 20.f) ? o.z : log1pf(__expf(o.z));
            o.w = (o.w > 20.f) ? o.w : log1pf(__expf(o.w));
            *(float4*)(sdw + (3*16 + c) * DST + q * 4) = o;
        }
        asm volatile("s_waitcnt lgkmcnt(0)" ::: "memory");
        __builtin_amdgcn_sched_barrier(0);
        // --- scan 16 timesteps (dt read back in t-order, 4 per ds_read_b128)
        const float* xp = xf + (grow0 + tb) * E_ + e;
        const ushort* skp = skipb + (grow0 + tb) * E_ + e;
        ushort* yp = y2 + (grow0 + tb) * E_ + e;
        #pragma unroll
        for (int u4 = 0; u4 < 4; ++u4){
            float4 dt4 = *(const float4*)(sdw + lane * DST + u4 * 4);
            #pragma unroll
            for (int j = 0; j < 4; ++j){
                int u = u4 * 4 + j;
                float dt = (j == 0) ? dt4.x : (j == 1) ? dt4.y : (j == 2) ? dt4.z : dt4.w;
                if (!PASS2) sdt += dt;
                const float* bc = sBC + (tb + u) * 32;
                float xu = xp[(size_t)u * E_];
                float dtx = dt * xu;
                float y0 = 0.f, y1 = 0.f;
                #pragma unroll
                for (int gg = 0; gg < 4; ++gg){
                    float4 Bv = *(const float4*)(bc + gg * 4);
                    h[gg*4+0] = __expf(dt * Aen[gg*4+0]) * h[gg*4+0] + dtx * Bv.x;
                    h[gg*4+1] = __expf(dt * Aen[gg*4+1]) * h[gg*4+1] + dtx * Bv.y;
                    h[gg*4+2] = __expf(dt * Aen[gg*4+2]) * h[gg*4+2] + dtx * Bv.z;
                    h[gg*4+3] = __expf(dt * Aen[gg*4+3]) * h[gg*4+3] + dtx * Bv.w;
                    if (PASS2){
                        float4 Cv = *(const float4*)(bc + 16 + gg * 4);
                        y0 += h[gg*4+0] * Cv.x + h[gg*4+1] * Cv.y;
                        y1 += h[gg*4+2] * Cv.z + h[gg*4+3] * Cv.w;
                    }
                }
                if (PASS2){
                    float sk = bf2f(skp[(size_t)u * E_]);
                    float gsk = sk / (1.f + __expf(-sk));
                    float yo = (y0 + y1 + wde * xu) * gsk;
                    yp[(size_t)u * E_] = f2bf(yo);
                }
            }
        }
    }
    if (!PASS2){
        float* Fp = F + ((size_t)(b * SSEG + seg) * E_ + e) * N_;
        #pragma unroll
        for (int g4 = 0; g4 < 4; ++g4){
            float4 v;
            v.x = h[g4*4+0]; v.y = h[g4*4+1]; v.z = h[g4*4+2]; v.w = h[g4*4+3];
            ((float4*)Fp)[g4] = v;
        }
        segdt[(size_t)(b * SSEG + seg) * E_ + e] = sdt;
    }
}

// sequential carry over SSEG segments per (b,e,n)
__global__ __launch_bounds__(256) void carry_k(const float* __restrict__ F,
                                               const float* __restrict__ segdt,
                                               const float* __restrict__ A_log,
                                               float* __restrict__ carr){
    int idx = blockIdx.x * 256 + threadIdx.x;      // over B_*E_*N_
    int n = idx & 15;
    int e = (idx >> 4) & (E_ - 1);
    int b = idx >> 15;
    const float Aen = -__expf(A_log[e * N_ + n]);
    float cacc = 0.f;
    for (int s = 0; s < SSEG; ++s){
        size_t base = ((size_t)(b * SSEG + s) * E_ + e) * N_ + n;
        carr[base] = cacc;
        float P = __expf(Aen * segdt[(size_t)(b * SSEG + s) * E_ + e]);
        cacc = P * cacc + F[base];
    }
}

// ---------------- launch ----------------
extern "C" void kernel_launch(void* const* d_in, const int* in_sizes, int n_in,
                              void* d_out, int out_size, void* d_ws, size_t ws_size,
                              hipStream_t stream){
    const float* resid  = (const float*)d_in[0];
    const float* norm_w = (const float*)d_in[1];
    const float* skip_w = (const float*)d_in[2];
    const float* in_w   = (const float*)d_in[3];
    const float* conv_w = (const float*)d_in[4];
    const float* conv_b = (const float*)d_in[5];
    const float* wd1    = (const float*)d_in[6];
    const float* wd2    = (const float*)d_in[7];
    const float* wd2_b  = (const float*)d_in[8];
    const float* wB     = (const float*)d_in[9];
    const float* wC     = (const float*)d_in[10];
    const float* A_log  = (const float*)d_in[11];
    const float* W_D    = (const float*)d_in[12];
    const float* out_w  = (const float*)d_in[13];
    float* out = (float*)d_out;

    char* ws = (char*)d_ws;
    size_t off = 0;
    auto alloc = [&](size_t bytes) -> char* {
        char* p = ws + off;
        off += (bytes + 255) & ~(size_t)255;
        return p;
    };
    // --- aliased region (32MB): wi, wsk, xn, xpre dead in stages; reused for
    //     split-K partials (16MB, dead after c96_reduce) then carr (16MB).
    char* alias_base = ws;
    ushort* wi_b    = (ushort*)alloc((size_t)E_ * D_ * 2);   // 4MB
    ushort* wsk_b   = (ushort*)alloc((size_t)E_ * D_ * 2);   // 4MB
    ushort* xn_b    = (ushort*)alloc((size_t)M_ * D_ * 2);   // 8MB
    ushort* xpre_b  = (ushort*)alloc((size_t)M_ * E_ * 2);   // 16MB
    float*  part_buf= (float*)alias_base;                    // 16MB alias (KS_*M_*128*4)
    float*  carr_buf= (float*)alias_base;                    // 16MB alias (after c96_reduce)
    // --- persistent buffers
    ushort* wo_b    = (ushort*)alloc((size_t)D_ * E_ * 2);       // 4MB
    ushort* wd2_bf  = (ushort*)alloc((size_t)E_ * DR_ * 2);      // 256KB
    ushort* W96_b   = (ushort*)alloc((size_t)128 * E_ * 2);      // 512KB
    ushort* skip_b  = (ushort*)alloc((size_t)M_ * E_ * 2);       // 16MB
    float*  xff     = (float*)alloc((size_t)M_ * E_ * 4);        // 32MB
    ushort* xb_b    = (ushort*)alloc((size_t)M_ * E_ * 2);       // 16MB
    ushort* C96_b   = (ushort*)alloc((size_t)M_ * 128 * 2);      // 1MB
    float*  scr     = (float*)alloc((size_t)M_ * E_ * 4);        // 32MB scratch slot
    ushort* y2_b    = (ushort*)alloc((size_t)M_ * E_ * 2);       // 16MB
    // sub-layout of scr: F (16MB) | segdt (1MB) | BCf (512KB)
    float* F_buf    = scr;
    float* segdt_buf= scr + (size_t)B_ * SSEG * E_ * N_;
    float* BCf_buf  = segdt_buf + (size_t)B_ * SSEG * E_;
    (void)ws_size; (void)in_sizes; (void)n_in; (void)out_size;

    const int thr = 256;
    auto blocks4 = [](int n){ return (n/4 + 255) / 256; };

    // weight conversions
    cvt4_k<<<blocks4(E_*D_), thr, 0, stream>>>(in_w,   wi_b,   E_*D_/4);
    cvt4_k<<<blocks4(E_*D_), thr, 0, stream>>>(skip_w, wsk_b,  E_*D_/4);
    cvt4_k<<<blocks4(D_*E_), thr, 0, stream>>>(out_w,  wo_b,   D_*E_/4);
    cvt4_k<<<blocks4(E_*DR_), thr, 0, stream>>>(wd2,   wd2_bf, E_*DR_/4);
    cvt4_k<<<blocks4(DR_*E_), thr, 0, stream>>>(wd1,   W96_b,            DR_*E_/4);
    cvt4_k<<<blocks4(N_*E_),  thr, 0, stream>>>(wB,    W96_b + 64*E_,    N_*E_/4);
    cvt4_k<<<blocks4(N_*E_),  thr, 0, stream>>>(wC,    W96_b + 80*E_,    N_*E_/4);
    zero16_k<<<(32*E_ + 255)/256, thr, 0, stream>>>(W96_b + 96*E_, 32*E_);

    // RMSNorm
    rmsnorm_k<<<M_, thr, 0, stream>>>(resid, norm_w, xn_b);

    // in-proj and skip-proj GEMMs: [4096,2048] = [4096,1024] x [2048,1024]^T
    gemm_bt<1><<<dim3(E_/BN, M_/BM), thr, 0, stream>>>(xn_b, wi_b,  xpre_b, nullptr, M_, E_, D_, D_, D_, E_);
    gemm_bt<1><<<dim3(E_/BN, M_/BM), thr, 0, stream>>>(xn_b, wsk_b, skip_b, nullptr, M_, E_, D_, D_, D_, E_);

    // conv + silu
    conv_silu_k<<<(M_*E_/4 + 255)/256, thr, 0, stream>>>(xpre_b, conv_w, conv_b, xff, xb_b);

    // C96[4096,128] = x[4096,2048] x W96[128,2048]^T, split-K x8 + reduce (+BCf f32)
    gemm_c96_sk<<<dim3(KS_, M_/BM), thr, 0, stream>>>(xb_b, W96_b, part_buf);
    c96_reduce_k<<<(M_*128/4)/256, thr, 0, stream>>>(part_buf, C96_b, BCf_buf);

    // chunk-parallel selective scan (n-in-register), gate fused into pass 2
    scan_k<0><<<dim3(E_/64, 16, B_), thr, 0, stream>>>(xff, C96_b, BCf_buf, wd2_bf, wd2_b, A_log,
                                                       nullptr, F_buf, segdt_buf, nullptr, nullptr, nullptr);
    carry_k<<<(B_*E_*N_)/256, thr, 0, stream>>>(F_buf, segdt_buf, A_log, carr_buf);
    scan_k<1><<<dim3(E_/64, 16, B_), thr, 0, stream>>>(xff, C96_b, BCf_buf, wd2_bf, wd2_b, A_log,
                                                       carr_buf, nullptr, nullptr, skip_b, W_D, y2_b);

    // out-proj + residual: out[4096,1024] = y2[4096,2048] x out_w[1024,2048]^T + resid
    gemm_bt<3><<<dim3(D_/BN, M_/BM), thr, 0, stream>>>(y2_b, wo_b, out, resid, M_, D_, E_, E_, E_, D_);
}

// Round 9
// 320.462 us; speedup vs baseline: 1.6465x; 1.6465x over previous
//
#include <hip/hip_runtime.h>
#include <hip/hip_bf16.h>

// Problem dims (fixed)
#define B_ 2
#define L_ 2048
#define D_ 1024
#define E_ 2048
#define N_ 16
#define DR_ 64
#define DC_ 4
#define M_ (B_*L_)   // 4096 rows
#define SSEG 16      // scan segments
#define LSEG (L_/SSEG)  // 128
#define KS_ 8        // split-K factor for C96 GEMM

typedef __attribute__((ext_vector_type(8))) short bf16x8;
typedef __attribute__((ext_vector_type(4))) float f32x4;

__device__ __forceinline__ ushort f2bf(float x){
    union { float f; unsigned u; } v; v.f = x;
    unsigned r = v.u + 0x7FFFu + ((v.u >> 16) & 1u);
    return (ushort)(r >> 16);
}
__device__ __forceinline__ float bf2f(ushort u){
    union { unsigned u; float f; } v; v.u = ((unsigned)u) << 16;
    return v.f;
}
// fast softplus: __logf instead of library log1pf (error ~1e-9 abs, negligible)
__device__ __forceinline__ float softplus_f(float z){
    return (z > 20.f) ? z : __logf(1.f + __expf(z));
}

// async global->LDS, 16B per lane. LDS dest = wave-uniform base + lane*16.
__device__ __forceinline__ void gld16(const void* g, void* l){
    __builtin_amdgcn_global_load_lds(
        (const __attribute__((address_space(1))) unsigned int*)g,
        (__attribute__((address_space(3))) unsigned int*)l,
        16, 0, 0);
}

// ---------------- convert f32 -> bf16 (vec4) ----------------
__global__ void cvt4_k(const float* __restrict__ in, ushort* __restrict__ out, int n4){
    int i = blockIdx.x * 256 + threadIdx.x;
    if (i < n4){
        float4 v = ((const float4*)in)[i];
        ushort4 o;
        o.x = f2bf(v.x); o.y = f2bf(v.y); o.z = f2bf(v.z); o.w = f2bf(v.w);
        ((ushort4*)out)[i] = o;
    }
}

__global__ void zero16_k(ushort* __restrict__ p, int n){
    int i = blockIdx.x * 256 + threadIdx.x;
    if (i < n) p[i] = 0;
}

// ---------------- RMSNorm -> bf16 ----------------
__global__ __launch_bounds__(256) void rmsnorm_k(const float* __restrict__ resid,
                                                 const float* __restrict__ norm_w,
                                                 ushort* __restrict__ xn){
    int row = blockIdx.x;
    const float4* r = (const float4*)(resid + (size_t)row * D_);
    float4 v = r[threadIdx.x];
    float ss = v.x*v.x + v.y*v.y + v.z*v.z + v.w*v.w;
    for (int m = 32; m; m >>= 1) ss += __shfl_xor(ss, m);
    __shared__ float sred[4];
    if ((threadIdx.x & 63) == 0) sred[threadIdx.x >> 6] = ss;
    __syncthreads();
    float tot = sred[0] + sred[1] + sred[2] + sred[3];
    float scale = rsqrtf(tot / (float)D_ + 1e-5f);
    const float4* wv = (const float4*)norm_w;
    float4 w = wv[threadIdx.x];
    ushort4 o;
    o.x = f2bf(v.x * scale * w.x);
    o.y = f2bf(v.y * scale * w.y);
    o.z = f2bf(v.z * scale * w.z);
    o.w = f2bf(v.w * scale * w.w);
    ((ushort4*)(xn + (size_t)row * D_))[threadIdx.x] = o;
}

// ---------------- GEMM: C[M,N] = A[M,K] * B[N,K]^T, bf16 in, f32 acc ----------------
// global_load_lds width-16 staging into LINEAR LDS [128][64] (m97 structure).
// EPI: 1 = bf16 store, 3 = acc + aux[idx] f32 store
#define BM 128
#define BN 128
#define BK 64

template<int EPI>
__global__ __launch_bounds__(256)
void gemm_bt(const ushort* __restrict__ A, const ushort* __restrict__ Bm,
             void* __restrict__ Cp, const float* __restrict__ aux,
             int M, int N, int K, int lda, int ldb, int ldc){
    __shared__ __align__(16) ushort As[BM * BK];
    __shared__ __align__(16) ushort Bs[BN * BK];
    const int col0 = blockIdx.x * BN;
    const int row0 = blockIdx.y * BM;
    const int tid = threadIdx.x;
    const int lane = tid & 63;
    const int wid = tid >> 6;
    const int wm = wid >> 1, wn = wid & 1;   // 2x2 waves of 64x64
    f32x4 acc[4][4] = {};

    const int l8 = lane >> 3;        // row within 8-row group
    const int c8 = (lane & 7) * 8;   // col (elements)

    for (int k0 = 0; k0 < K; k0 += BK){
        #pragma unroll
        for (int i = 0; i < 4; ++i){
            const int R0 = wid * 32 + i * 8;   // 8 rows per instr
            gld16(A + (size_t)(row0 + R0 + l8) * lda + k0 + c8, As + R0 * BK);
            gld16(Bm + (size_t)(col0 + R0 + l8) * ldb + k0 + c8, Bs + R0 * BK);
        }
        __syncthreads();   // drains vmcnt before barrier
        #pragma unroll
        for (int kk = 0; kk < 2; ++kk){
            bf16x8 af[4], bfr[4];
            const int krow = lane & 15;
            const int kcol = kk * 32 + (lane >> 4) * 8;
            #pragma unroll
            for (int mi = 0; mi < 4; ++mi)
                af[mi] = *(const bf16x8*)(As + (wm*64 + mi*16 + krow) * BK + kcol);
            #pragma unroll
            for (int ni = 0; ni < 4; ++ni)
                bfr[ni] = *(const bf16x8*)(Bs + (wn*64 + ni*16 + krow) * BK + kcol);
            #pragma unroll
            for (int mi = 0; mi < 4; ++mi)
                #pragma unroll
                for (int ni = 0; ni < 4; ++ni)
                    acc[mi][ni] = __builtin_amdgcn_mfma_f32_16x16x32_bf16(af[mi], bfr[ni], acc[mi][ni], 0, 0, 0);
        }
        __syncthreads();
    }

    #pragma unroll
    for (int mi = 0; mi < 4; ++mi)
        #pragma unroll
        for (int ni = 0; ni < 4; ++ni)
            #pragma unroll
            for (int j = 0; j < 4; ++j){
                int r = row0 + wm*64 + mi*16 + (lane >> 4) * 4 + j;
                int c = col0 + wn*64 + ni*16 + (lane & 15);
                size_t idx = (size_t)r * ldc + c;
                float v = acc[mi][ni][j];
                if (EPI == 1){
                    ((ushort*)Cp)[idx] = f2bf(v);
                } else {
                    ((float*)Cp)[idx] = v + aux[idx];
                }
            }
}

// ---------------- C96 GEMM, split-K: part[ks][4096][128] f32 partials ----------------
__global__ __launch_bounds__(256)
void gemm_c96_sk(const ushort* __restrict__ A, const ushort* __restrict__ Bm,
                 float* __restrict__ part){
    __shared__ __align__(16) ushort As[BM * BK];
    __shared__ __align__(16) ushort Bs[BN * BK];
    const int ks = blockIdx.x;
    const int row0 = blockIdx.y * BM;
    const int tid = threadIdx.x;
    const int lane = tid & 63;
    const int wid = tid >> 6;
    const int wm = wid >> 1, wn = wid & 1;
    f32x4 acc[4][4] = {};
    const int l8 = lane >> 3;
    const int c8 = (lane & 7) * 8;

    for (int k0 = ks * (E_ / KS_); k0 < (ks + 1) * (E_ / KS_); k0 += BK){
        #pragma unroll
        for (int i = 0; i < 4; ++i){
            const int R0 = wid * 32 + i * 8;
            gld16(A + (size_t)(row0 + R0 + l8) * E_ + k0 + c8, As + R0 * BK);
            gld16(Bm + (size_t)(R0 + l8) * E_ + k0 + c8, Bs + R0 * BK);
        }
        __syncthreads();
        #pragma unroll
        for (int kk = 0; kk < 2; ++kk){
            bf16x8 af[4], bfr[4];
            const int krow = lane & 15;
            const int kcol = kk * 32 + (lane >> 4) * 8;
            #pragma unroll
            for (int mi = 0; mi < 4; ++mi)
                af[mi] = *(const bf16x8*)(As + (wm*64 + mi*16 + krow) * BK + kcol);
            #pragma unroll
            for (int ni = 0; ni < 4; ++ni)
                bfr[ni] = *(const bf16x8*)(Bs + (wn*64 + ni*16 + krow) * BK + kcol);
            #pragma unroll
            for (int mi = 0; mi < 4; ++mi)
                #pragma unroll
                for (int ni = 0; ni < 4; ++ni)
                    acc[mi][ni] = __builtin_amdgcn_mfma_f32_16x16x32_bf16(af[mi], bfr[ni], acc[mi][ni], 0, 0, 0);
        }
        __syncthreads();
    }
    float* dst = part + (size_t)ks * M_ * 128;
    #pragma unroll
    for (int mi = 0; mi < 4; ++mi)
        #pragma unroll
        for (int ni = 0; ni < 4; ++ni)
            #pragma unroll
            for (int j = 0; j < 4; ++j){
                int r = row0 + wm*64 + mi*16 + (lane >> 4) * 4 + j;
                int c = wn*64 + ni*16 + (lane & 15);
                dst[(size_t)r * 128 + c] = acc[mi][ni][j];
            }
}

__global__ __launch_bounds__(256) void c96_reduce_k(const float* __restrict__ part,
                                                    ushort* __restrict__ C96){
    int i4 = blockIdx.x * 256 + threadIdx.x;     // over M_*128/4
    float4 a = *(const float4*)(part + (size_t)i4 * 4);
    #pragma unroll
    for (int k = 1; k < KS_; ++k){
        float4 b = *(const float4*)(part + (size_t)k * M_ * 128 + (size_t)i4 * 4);
        a.x += b.x; a.y += b.y; a.z += b.z; a.w += b.w;
    }
    ushort4 o;
    o.x = f2bf(a.x); o.y = f2bf(a.y); o.z = f2bf(a.z); o.w = f2bf(a.w);
    *(ushort4*)(C96 + (size_t)i4 * 4) = o;
}

// ---------------- causal depthwise conv1d + silu (vec4 along e) ----------------
__global__ __launch_bounds__(256) void conv_silu_k(const ushort* __restrict__ xpre,
                                                   const float* __restrict__ conv_w,
                                                   const float* __restrict__ conv_b,
                                                   float* __restrict__ xf,
                                                   ushort* __restrict__ xb){
    int i4 = blockIdx.x * 256 + threadIdx.x;
    if (i4 >= M_ * E_ / 4) return;
    int idx = i4 * 4;
    int e = idx & (E_ - 1);
    int bl = idx >> 11;
    int t = bl & (L_ - 1);
    float acc[4];
    #pragma unroll
    for (int j = 0; j < 4; ++j) acc[j] = conv_b[e + j];
    #pragma unroll
    for (int k = 0; k < 4; ++k){
        int dt = 3 - k;
        if (t >= dt){
            ushort4 xv = *(const ushort4*)(xpre + idx - dt * E_);
            acc[0] += bf2f(xv.x) * conv_w[(e+0)*4 + k];
            acc[1] += bf2f(xv.y) * conv_w[(e+1)*4 + k];
            acc[2] += bf2f(xv.z) * conv_w[(e+2)*4 + k];
            acc[3] += bf2f(xv.w) * conv_w[(e+3)*4 + k];
        }
    }
    float4 so; ushort4 sb;
    float* sp = (float*)&so;
    #pragma unroll
    for (int j = 0; j < 4; ++j){
        float s = acc[j] / (1.f + __expf(-acc[j]));
        sp[j] = s;
    }
    sb.x = f2bf(so.x); sb.y = f2bf(so.y); sb.z = f2bf(so.z); sb.w = f2bf(so.w);
    *(float4*)(xf + idx) = so;
    *(ushort4*)(xb + idx) = sb;
}

// ---------------- chunk-parallel selective scan, delta fused via MFMA ----------------
// delta[t,e] = softplus(dot64(xr[t,:], wd2[e,:]) + wd2_b[e]); xr = C96 cols 0..63.
// Pass 1 (seg1): local scan from 0 -> F, segdt. Pass 2 (carry_k). Pass 3 (seg2): y,
// with the output gate fused into seg2's store (y2 = (y + W_D*x)*silu(skip) -> bf16).
// [r8 lesson: this seg structure (measured 94+60 us) beats the n-in-register redesign
//  (150+150 us) -- keep it and improve incrementally.]
#define SLDF 68   // float tile stride (272B, 16B-aligned)
#define SLDH 72   // ushort tile stride (144B, 16B-aligned)

// grid (E_/16, SSEG, B_), block 256 = 16 e x 16 n
__global__ __launch_bounds__(256) void seg1_k(const float* __restrict__ xf,
                                              const ushort* __restrict__ C96,
                                              const ushort* __restrict__ wd2b,
                                              const float* __restrict__ wd2_bias,
                                              const float* __restrict__ A_log,
                                              float* __restrict__ F,
                                              float* __restrict__ segdt){
    const int b = blockIdx.z, s = blockIdx.y, e0 = blockIdx.x * 16;
    const int tid = threadIdx.x;
    const int lane = tid & 63, wid = tid >> 6;
    const int n = tid & 15, ei = tid >> 4;
    const int e = e0 + ei;
    const float Aen = -__expf(A_log[e * N_ + n]);
    float h = 0.f, sdt = 0.f;
    __shared__ __align__(16) ushort sxr[64][SLDH];
    __shared__ __align__(16) ushort swd2[16][SLDH];
    __shared__ float sd[16][SLDF], sx[16][SLDF], sB[16][SLDF];
    const int tq = tid >> 2, qc = tid & 3;

    if (tid < 128){
        int r = tid >> 3, cc = (tid & 7) * 8;
        *(uint4*)&swd2[r][cc] = *(const uint4*)(wd2b + (size_t)(e0 + r) * DR_ + cc);
    }
    const float bias = wd2_bias[e0 + (lane & 15)];

    for (int c = 0; c < LSEG / 64; ++c){
        int t0 = s * LSEG + c * 64;
        size_t row = (size_t)(b * L_ + t0 + tq);
        *(uint4*)&sxr[tq][qc * 16]     = *(const uint4*)(C96 + row * 128 + qc * 16);
        *(uint4*)&sxr[tq][qc * 16 + 8] = *(const uint4*)(C96 + row * 128 + qc * 16 + 8);
        ushort4 rB = *(const ushort4*)(C96 + row * 128 + 64 + qc * 4);
        float4  rx = *(const float4*)(xf + row * E_ + e0 + qc * 4);
        sB[qc*4+0][tq] = bf2f(rB.x); sB[qc*4+1][tq] = bf2f(rB.y);
        sB[qc*4+2][tq] = bf2f(rB.z); sB[qc*4+3][tq] = bf2f(rB.w);
        sx[qc*4+0][tq] = rx.x; sx[qc*4+1][tq] = rx.y;
        sx[qc*4+2][tq] = rx.z; sx[qc*4+3][tq] = rx.w;
        __syncthreads();
        // fused delta: wave wid computes t rows wid*16..+15 x 16 e's
        f32x4 dacc = {};
        #pragma unroll
        for (int kk = 0; kk < 2; ++kk){
            bf16x8 af = *(const bf16x8*)&sxr[wid*16 + (lane & 15)][kk*32 + (lane >> 4)*8];
            bf16x8 bf = *(const bf16x8*)&swd2[lane & 15][kk*32 + (lane >> 4)*8];
            dacc = __builtin_amdgcn_mfma_f32_16x16x32_bf16(af, bf, dacc, 0, 0, 0);
        }
        #pragma unroll
        for (int j = 0; j < 4; ++j){
            int tt = wid*16 + (lane >> 4)*4 + j;
            sd[lane & 15][tt] = softplus_f(dacc[j] + bias);
        }
        __syncthreads();
        #pragma unroll
        for (int t = 0; t < 64; t += 4){
            float4 d4 = *(const float4*)&sd[ei][t];
            float4 x4 = *(const float4*)&sx[ei][t];
            float4 b4 = *(const float4*)&sB[n][t];
            h = __expf(d4.x*Aen)*h + d4.x*x4.x*b4.x;
            h = __expf(d4.y*Aen)*h + d4.y*x4.y*b4.y;
            h = __expf(d4.z*Aen)*h + d4.z*x4.z*b4.z;
            h = __expf(d4.w*Aen)*h + d4.w*x4.w*b4.w;
            sdt += d4.x + d4.y + d4.z + d4.w;
        }
        __syncthreads();
    }
    size_t base = ((size_t)(b * SSEG + s) * E_ + e) * N_ + n;
    F[base] = h;
    if (n == 0) segdt[(size_t)(b * SSEG + s) * E_ + e] = sdt;
}

// sequential carry over SSEG segments per (b,e,n)
__global__ __launch_bounds__(256) void carry_k(const float* __restrict__ F,
                                               const float* __restrict__ segdt,
                                               const float* __restrict__ A_log,
                                               float* __restrict__ carr){
    int idx = blockIdx.x * 256 + threadIdx.x;
    int n = idx & 15;
    int e = (idx >> 4) & (E_ - 1);
    int b = idx >> 15;
    const float Aen = -__expf(A_log[e * N_ + n]);
    float c = 0.f;
    #pragma unroll
    for (int s = 0; s < SSEG; ++s){
        size_t base = ((size_t)(b * SSEG + s) * E_ + e) * N_ + n;
        carr[base] = c;
        float P = __expf(Aen * segdt[(size_t)(b * SSEG + s) * E_ + e]);
        c = P * c + F[base];
    }
}

// grid (E_/16, SSEG, B_), block 256; gate fused into store
__global__ __launch_bounds__(256) void seg2_k(const float* __restrict__ xf,
                                              const ushort* __restrict__ C96,
                                              const ushort* __restrict__ wd2b,
                                              const float* __restrict__ wd2_bias,
                                              const float* __restrict__ A_log,
                                              const float* __restrict__ carr,
                                              const ushort* __restrict__ skipb,
                                              const float* __restrict__ W_D,
                                              ushort* __restrict__ y2){
    const int b = blockIdx.z, s = blockIdx.y, e0 = blockIdx.x * 16;
    const int tid = threadIdx.x;
    const int lane = tid & 63, wid = tid >> 6;
    const int n = tid & 15, ei = tid >> 4;
    const int e = e0 + ei;
    const float Aen = -__expf(A_log[e * N_ + n]);
    float h = carr[((size_t)(b * SSEG + s) * E_ + e) * N_ + n];
    __shared__ __align__(16) ushort sxr[64][SLDH];
    __shared__ __align__(16) ushort swd2[16][SLDH];
    __shared__ float sd[16][SLDF], sx[16][SLDF], sB[16][SLDF], sC[16][SLDF];
    __shared__ float sy[64][16];
    const int tq = tid >> 2, qc = tid & 3;

    if (tid < 128){
        int r = tid >> 3, cc = (tid & 7) * 8;
        *(uint4*)&swd2[r][cc] = *(const uint4*)(wd2b + (size_t)(e0 + r) * DR_ + cc);
    }
    const float bias = wd2_bias[e0 + (lane & 15)];
    const float4 wv = *(const float4*)(W_D + e0 + qc * 4);

    for (int c = 0; c < LSEG / 64; ++c){
        int t0 = s * LSEG + c * 64;
        size_t row = (size_t)(b * L_ + t0 + tq);
        *(uint4*)&sxr[tq][qc * 16]     = *(const uint4*)(C96 + row * 128 + qc * 16);
        *(uint4*)&sxr[tq][qc * 16 + 8] = *(const uint4*)(C96 + row * 128 + qc * 16 + 8);
        ushort4 rB = *(const ushort4*)(C96 + row * 128 + 64 + qc * 4);
        ushort4 rC = *(const ushort4*)(C96 + row * 128 + 80 + qc * 4);
        float4  rx = *(const float4*)(xf + row * E_ + e0 + qc * 4);
        sB[qc*4+0][tq] = bf2f(rB.x); sB[qc*4+1][tq] = bf2f(rB.y);
        sB[qc*4+2][tq] = bf2f(rB.z); sB[qc*4+3][tq] = bf2f(rB.w);
        sC[qc*4+0][tq] = bf2f(rC.x); sC[qc*4+1][tq] = bf2f(rC.y);
        sC[qc*4+2][tq] = bf2f(rC.z); sC[qc*4+3][tq] = bf2f(rC.w);
        sx[qc*4+0][tq] = rx.x; sx[qc*4+1][tq] = rx.y;
        sx[qc*4+2][tq] = rx.z; sx[qc*4+3][tq] = rx.w;
        __syncthreads();
        f32x4 dacc = {};
        #pragma unroll
        for (int kk = 0; kk < 2; ++kk){
            bf16x8 af = *(const bf16x8*)&sxr[wid*16 + (lane & 15)][kk*32 + (lane >> 4)*8];
            bf16x8 bf = *(const bf16x8*)&swd2[lane & 15][kk*32 + (lane >> 4)*8];
            dacc = __builtin_amdgcn_mfma_f32_16x16x32_bf16(af, bf, dacc, 0, 0, 0);
        }
        #pragma unroll
        for (int j = 0; j < 4; ++j){
            int tt = wid*16 + (lane >> 4)*4 + j;
            sd[lane & 15][tt] = softplus_f(dacc[j] + bias);
        }
        __syncthreads();
        #pragma unroll
        for (int t = 0; t < 64; t += 4){
            float4 d4 = *(const float4*)&sd[ei][t];
            float4 x4 = *(const float4*)&sx[ei][t];
            float4 b4 = *(const float4*)&sB[n][t];
            float4 c4 = *(const float4*)&sC[n][t];
            float y0, y1, y2v, y3;
            h = __expf(d4.x*Aen)*h + d4.x*x4.x*b4.x;  y0 = h * c4.x;
            h = __expf(d4.y*Aen)*h + d4.y*x4.y*b4.y;  y1 = h * c4.y;
            h = __expf(d4.z*Aen)*h + d4.z*x4.z*b4.z;  y2v = h * c4.z;
            h = __expf(d4.w*Aen)*h + d4.w*x4.w*b4.w;  y3 = h * c4.w;
            // 4-value 16-lane butterfly reduce: 5 shfls
            float s01 = (n & 1) ? y0 : y1;
            float r01 = __shfl_xor(s01, 1);
            float s23 = (n & 1) ? y2v : y3;
            float r23 = __shfl_xor(s23, 1);
            float va, vb;
            if (n & 1){ va = y1 + r01; vb = y3 + r23; }
            else      { va = y0 + r01; vb = y2v + r23; }
            float s2 = (n & 2) ? va : vb;
            float r2 = __shfl_xor(s2, 2);
            float v = ((n & 2) ? vb : va) + r2;
            v += __shfl_xor(v, 4);
            v += __shfl_xor(v, 8);
            if (n < 4) sy[t + n][ei] = v;
        }
        __syncthreads();
        {
            // fused gate: y2 = (y + W_D*x) * silu(skip) -> bf16
            size_t orow = (size_t)(b * L_ + t0 + tq);
            float4 yv = *(float4*)&sy[tq][qc * 4];
            float xs0 = sx[qc*4+0][tq], xs1 = sx[qc*4+1][tq];
            float xs2 = sx[qc*4+2][tq], xs3 = sx[qc*4+3][tq];
            ushort4 sv = *(const ushort4*)(skipb + orow * E_ + e0 + qc * 4);
            float sk0 = bf2f(sv.x), sk1 = bf2f(sv.y), sk2 = bf2f(sv.z), sk3 = bf2f(sv.w);
            ushort4 o;
            o.x = f2bf((yv.x + wv.x * xs0) * (sk0 / (1.f + __expf(-sk0))));
            o.y = f2bf((yv.y + wv.y * xs1) * (sk1 / (1.f + __expf(-sk1))));
            o.z = f2bf((yv.z + wv.z * xs2) * (sk2 / (1.f + __expf(-sk2))));
            o.w = f2bf((yv.w + wv.w * xs3) * (sk3 / (1.f + __expf(-sk3))));
            *(ushort4*)(y2 + orow * E_ + e0 + qc * 4) = o;
        }
        __syncthreads();
    }
}

// ---------------- launch ----------------
extern "C" void kernel_launch(void* const* d_in, const int* in_sizes, int n_in,
                              void* d_out, int out_size, void* d_ws, size_t ws_size,
                              hipStream_t stream){
    const float* resid  = (const float*)d_in[0];
    const float* norm_w = (const float*)d_in[1];
    const float* skip_w = (const float*)d_in[2];
    const float* in_w   = (const float*)d_in[3];
    const float* conv_w = (const float*)d_in[4];
    const float* conv_b = (const float*)d_in[5];
    const float* wd1    = (const float*)d_in[6];
    const float* wd2    = (const float*)d_in[7];
    const float* wd2_b  = (const float*)d_in[8];
    const float* wB     = (const float*)d_in[9];
    const float* wC     = (const float*)d_in[10];
    const float* A_log  = (const float*)d_in[11];
    const float* W_D    = (const float*)d_in[12];
    const float* out_w  = (const float*)d_in[13];
    float* out = (float*)d_out;

    char* ws = (char*)d_ws;
    size_t off = 0;
    auto alloc = [&](size_t bytes) -> char* {
        char* p = ws + off;
        off += (bytes + 255) & ~(size_t)255;
        return p;
    };
    // --- aliased region: wi, wsk, xn (16MB) dead before the C96 GEMM runs;
    //     split-K partial buffer (16MB f32) reuses them.
    char* alias_base = ws;
    ushort* wi_b    = (ushort*)alloc((size_t)E_ * D_ * 2);   // 4MB
    ushort* wsk_b   = (ushort*)alloc((size_t)E_ * D_ * 2);   // 4MB
    ushort* xn_b    = (ushort*)alloc((size_t)M_ * D_ * 2);   // 8MB
    ushort* xpre_b  = (ushort*)alloc((size_t)M_ * E_ * 2);   // 16MB
    float*  part_buf= (float*)alias_base;                    // 16MB alias (KS_*M_*128*4)
    // --- persistent buffers
    ushort* wo_b    = (ushort*)alloc((size_t)D_ * E_ * 2);       // 4MB
    ushort* wd2_bf  = (ushort*)alloc((size_t)E_ * DR_ * 2);      // 256KB
    ushort* W96_b   = (ushort*)alloc((size_t)128 * E_ * 2);      // 512KB
    ushort* skip_b  = (ushort*)alloc((size_t)M_ * E_ * 2);       // 16MB
    float*  xff     = (float*)alloc((size_t)M_ * E_ * 4);        // 32MB
    ushort* xb_b    = (ushort*)alloc((size_t)M_ * E_ * 2);       // 16MB
    ushort* C96_b   = (ushort*)alloc((size_t)M_ * 128 * 2);      // 1MB
    float*  scr     = (float*)alloc((size_t)M_ * E_ * 4);        // 32MB scratch slot
    ushort* y2_b    = (ushort*)alloc((size_t)M_ * E_ * 2);       // 16MB
    // sub-layout of scr: F (4MB) | carr (4MB) | segdt (256KB)
    float* F_buf    = scr;
    float* carr_buf = scr + (size_t)B_ * SSEG * E_ * N_;
    float* segdt_buf= scr + (size_t)2 * B_ * SSEG * E_ * N_;
    (void)ws_size; (void)in_sizes; (void)n_in; (void)out_size;

    const int thr = 256;
    auto blocks4 = [](int n){ return (n/4 + 255) / 256; };

    // weight conversions
    cvt4_k<<<blocks4(E_*D_), thr, 0, stream>>>(in_w,   wi_b,   E_*D_/4);
    cvt4_k<<<blocks4(E_*D_), thr, 0, stream>>>(skip_w, wsk_b,  E_*D_/4);
    cvt4_k<<<blocks4(D_*E_), thr, 0, stream>>>(out_w,  wo_b,   D_*E_/4);
    cvt4_k<<<blocks4(E_*DR_), thr, 0, stream>>>(wd2,   wd2_bf, E_*DR_/4);
    cvt4_k<<<blocks4(DR_*E_), thr, 0, stream>>>(wd1,   W96_b,            DR_*E_/4);
    cvt4_k<<<blocks4(N_*E_),  thr, 0, stream>>>(wB,    W96_b + 64*E_,    N_*E_/4);
    cvt4_k<<<blocks4(N_*E_),  thr, 0, stream>>>(wC,    W96_b + 80*E_,    N_*E_/4);
    zero16_k<<<(32*E_ + 255)/256, thr, 0, stream>>>(W96_b + 96*E_, 32*E_);

    // RMSNorm
    rmsnorm_k<<<M_, thr, 0, stream>>>(resid, norm_w, xn_b);

    // in-proj and skip-proj GEMMs: [4096,2048] = [4096,1024] x [2048,1024]^T
    gemm_bt<1><<<dim3(E_/BN, M_/BM), thr, 0, stream>>>(xn_b, wi_b,  xpre_b, nullptr, M_, E_, D_, D_, D_, E_);
    gemm_bt<1><<<dim3(E_/BN, M_/BM), thr, 0, stream>>>(xn_b, wsk_b, skip_b, nullptr, M_, E_, D_, D_, D_, E_);

    // conv + silu
    conv_silu_k<<<(M_*E_/4 + 255)/256, thr, 0, stream>>>(xpre_b, conv_w, conv_b, xff, xb_b);

    // C96[4096,128] = x[4096,2048] x W96[128,2048]^T, split-K x8 + reduce
    gemm_c96_sk<<<dim3(KS_, M_/BM), thr, 0, stream>>>(xb_b, W96_b, part_buf);
    c96_reduce_k<<<(M_*128/4)/256, thr, 0, stream>>>(part_buf, C96_b);

    // chunk-parallel selective scan with fused delta; gate fused into seg2
    seg1_k<<<dim3(E_/16, SSEG, B_), thr, 0, stream>>>(xff, C96_b, wd2_bf, wd2_b, A_log, F_buf, segdt_buf);
    carry_k<<<(B_*E_*N_)/256, thr, 0, stream>>>(F_buf, segdt_buf, A_log, carr_buf);
    seg2_k<<<dim3(E_/16, SSEG, B_), thr, 0, stream>>>(xff, C96_b, wd2_bf, wd2_b, A_log, carr_buf,
                                                      skip_b, W_D, y2_b);

    // out-proj + residual: out[4096,1024] = y2[4096,2048] x out_w[1024,2048]^T + resid
    gemm_bt<3><<<dim3(D_/BN, M_/BM), thr, 0, stream>>>(y2_b, wo_b, out, resid, M_, D_, E_, E_, E_, D_);
}

// Round 10
// 313.655 us; speedup vs baseline: 1.6823x; 1.0217x over previous
//
#include <hip/hip_runtime.h>
#include <hip/hip_bf16.h>

// Problem dims (fixed)
#define B_ 2
#define L_ 2048
#define D_ 1024
#define E_ 2048
#define N_ 16
#define DR_ 64
#define DC_ 4
#define M_ (B_*L_)   // 4096 rows
#define SSEG 16      // scan segments
#define LSEG (L_/SSEG)  // 128
#define KS_ 8        // split-K factor for C96 GEMM

typedef __attribute__((ext_vector_type(8))) short bf16x8;
typedef __attribute__((ext_vector_type(4))) float f32x4;

__device__ __forceinline__ ushort f2bf(float x){
    union { float f; unsigned u; } v; v.f = x;
    unsigned r = v.u + 0x7FFFu + ((v.u >> 16) & 1u);
    return (ushort)(r >> 16);
}
__device__ __forceinline__ float bf2f(ushort u){
    union { unsigned u; float f; } v; v.u = ((unsigned)u) << 16;
    return v.f;
}
// fast softplus: __logf instead of library log1pf (error ~1e-9 abs, negligible)
__device__ __forceinline__ float softplus_f(float z){
    return (z > 20.f) ? z : __logf(1.f + __expf(z));
}

// async global->LDS, 16B per lane. LDS dest = wave-uniform base + lane*16.
__device__ __forceinline__ void gld16(const void* g, void* l){
    __builtin_amdgcn_global_load_lds(
        (const __attribute__((address_space(1))) unsigned int*)g,
        (__attribute__((address_space(3))) unsigned int*)l,
        16, 0, 0);
}

// ---------------- convert f32 -> bf16 (vec4) ----------------
__global__ void cvt4_k(const float* __restrict__ in, ushort* __restrict__ out, int n4){
    int i = blockIdx.x * 256 + threadIdx.x;
    if (i < n4){
        float4 v = ((const float4*)in)[i];
        ushort4 o;
        o.x = f2bf(v.x); o.y = f2bf(v.y); o.z = f2bf(v.z); o.w = f2bf(v.w);
        ((ushort4*)out)[i] = o;
    }
}

__global__ void zero16_k(ushort* __restrict__ p, int n){
    int i = blockIdx.x * 256 + threadIdx.x;
    if (i < n) p[i] = 0;
}

// ---------------- RMSNorm -> bf16 ----------------
__global__ __launch_bounds__(256) void rmsnorm_k(const float* __restrict__ resid,
                                                 const float* __restrict__ norm_w,
                                                 ushort* __restrict__ xn){
    int row = blockIdx.x;
    const float4* r = (const float4*)(resid + (size_t)row * D_);
    float4 v = r[threadIdx.x];
    float ss = v.x*v.x + v.y*v.y + v.z*v.z + v.w*v.w;
    for (int m = 32; m; m >>= 1) ss += __shfl_xor(ss, m);
    __shared__ float sred[4];
    if ((threadIdx.x & 63) == 0) sred[threadIdx.x >> 6] = ss;
    __syncthreads();
    float tot = sred[0] + sred[1] + sred[2] + sred[3];
    float scale = rsqrtf(tot / (float)D_ + 1e-5f);
    const float4* wv = (const float4*)norm_w;
    float4 w = wv[threadIdx.x];
    ushort4 o;
    o.x = f2bf(v.x * scale * w.x);
    o.y = f2bf(v.y * scale * w.y);
    o.z = f2bf(v.z * scale * w.z);
    o.w = f2bf(v.w * scale * w.w);
    ((ushort4*)(xn + (size_t)row * D_))[threadIdx.x] = o;
}

// ---------------- GEMM machinery (m97 structure, global_load_lds staging) ----------------
#define BM 128
#define BN 128
#define BK 64

// fused in-proj + skip-proj: Bm = [in_w ; skip_w] stacked (N = 2*E_),
// cols < E_ -> P1 (xpre), cols >= E_ -> P2 (skip). bf16 store.
__global__ __launch_bounds__(256)
void gemm_dual_k(const ushort* __restrict__ A, const ushort* __restrict__ Bm,
                 ushort* __restrict__ P1, ushort* __restrict__ P2){
    __shared__ __align__(16) ushort As[BM * BK];
    __shared__ __align__(16) ushort Bs[BN * BK];
    const int col0 = blockIdx.x * BN;    // 0..4095
    const int row0 = blockIdx.y * BM;
    const int tid = threadIdx.x;
    const int lane = tid & 63;
    const int wid = tid >> 6;
    const int wm = wid >> 1, wn = wid & 1;
    f32x4 acc[4][4] = {};
    const int l8 = lane >> 3;
    const int c8 = (lane & 7) * 8;

    for (int k0 = 0; k0 < D_; k0 += BK){
        #pragma unroll
        for (int i = 0; i < 4; ++i){
            const int R0 = wid * 32 + i * 8;
            gld16(A + (size_t)(row0 + R0 + l8) * D_ + k0 + c8, As + R0 * BK);
            gld16(Bm + (size_t)(col0 + R0 + l8) * D_ + k0 + c8, Bs + R0 * BK);
        }
        __syncthreads();
        #pragma unroll
        for (int kk = 0; kk < 2; ++kk){
            bf16x8 af[4], bfr[4];
            const int krow = lane & 15;
            const int kcol = kk * 32 + (lane >> 4) * 8;
            #pragma unroll
            for (int mi = 0; mi < 4; ++mi)
                af[mi] = *(const bf16x8*)(As + (wm*64 + mi*16 + krow) * BK + kcol);
            #pragma unroll
            for (int ni = 0; ni < 4; ++ni)
                bfr[ni] = *(const bf16x8*)(Bs + (wn*64 + ni*16 + krow) * BK + kcol);
            #pragma unroll
            for (int mi = 0; mi < 4; ++mi)
                #pragma unroll
                for (int ni = 0; ni < 4; ++ni)
                    acc[mi][ni] = __builtin_amdgcn_mfma_f32_16x16x32_bf16(af[mi], bfr[ni], acc[mi][ni], 0, 0, 0);
        }
        __syncthreads();
    }
    ushort* base = (col0 < E_) ? P1 : P2;
    const int cb = (col0 < E_) ? col0 : col0 - E_;
    #pragma unroll
    for (int mi = 0; mi < 4; ++mi)
        #pragma unroll
        for (int ni = 0; ni < 4; ++ni)
            #pragma unroll
            for (int j = 0; j < 4; ++j){
                int r = row0 + wm*64 + mi*16 + (lane >> 4) * 4 + j;
                int c = cb + wn*64 + ni*16 + (lane & 15);
                base[(size_t)r * E_ + c] = f2bf(acc[mi][ni][j]);
            }
}

// out-proj: C[M,N] f32 = A x B^T + aux (residual)
__global__ __launch_bounds__(256)
void gemm_out_k(const ushort* __restrict__ A, const ushort* __restrict__ Bm,
                float* __restrict__ Cp, const float* __restrict__ aux){
    __shared__ __align__(16) ushort As[BM * BK];
    __shared__ __align__(16) ushort Bs[BN * BK];
    const int col0 = blockIdx.x * BN;
    const int row0 = blockIdx.y * BM;
    const int tid = threadIdx.x;
    const int lane = tid & 63;
    const int wid = tid >> 6;
    const int wm = wid >> 1, wn = wid & 1;
    f32x4 acc[4][4] = {};
    const int l8 = lane >> 3;
    const int c8 = (lane & 7) * 8;

    for (int k0 = 0; k0 < E_; k0 += BK){
        #pragma unroll
        for (int i = 0; i < 4; ++i){
            const int R0 = wid * 32 + i * 8;
            gld16(A + (size_t)(row0 + R0 + l8) * E_ + k0 + c8, As + R0 * BK);
            gld16(Bm + (size_t)(col0 + R0 + l8) * E_ + k0 + c8, Bs + R0 * BK);
        }
        __syncthreads();
        #pragma unroll
        for (int kk = 0; kk < 2; ++kk){
            bf16x8 af[4], bfr[4];
            const int krow = lane & 15;
            const int kcol = kk * 32 + (lane >> 4) * 8;
            #pragma unroll
            for (int mi = 0; mi < 4; ++mi)
                af[mi] = *(const bf16x8*)(As + (wm*64 + mi*16 + krow) * BK + kcol);
            #pragma unroll
            for (int ni = 0; ni < 4; ++ni)
                bfr[ni] = *(const bf16x8*)(Bs + (wn*64 + ni*16 + krow) * BK + kcol);
            #pragma unroll
            for (int mi = 0; mi < 4; ++mi)
                #pragma unroll
                for (int ni = 0; ni < 4; ++ni)
                    acc[mi][ni] = __builtin_amdgcn_mfma_f32_16x16x32_bf16(af[mi], bfr[ni], acc[mi][ni], 0, 0, 0);
        }
        __syncthreads();
    }
    #pragma unroll
    for (int mi = 0; mi < 4; ++mi)
        #pragma unroll
        for (int ni = 0; ni < 4; ++ni)
            #pragma unroll
            for (int j = 0; j < 4; ++j){
                int r = row0 + wm*64 + mi*16 + (lane >> 4) * 4 + j;
                int c = col0 + wn*64 + ni*16 + (lane & 15);
                size_t idx = (size_t)r * D_ + c;
                Cp[idx] = acc[mi][ni][j] + aux[idx];
            }
}

// ---------------- C96 GEMM, split-K: part[ks][4096][128] f32 partials ----------------
__global__ __launch_bounds__(256)
void gemm_c96_sk(const ushort* __restrict__ A, const ushort* __restrict__ Bm,
                 float* __restrict__ part){
    __shared__ __align__(16) ushort As[BM * BK];
    __shared__ __align__(16) ushort Bs[BN * BK];
    const int ks = blockIdx.x;
    const int row0 = blockIdx.y * BM;
    const int tid = threadIdx.x;
    const int lane = tid & 63;
    const int wid = tid >> 6;
    const int wm = wid >> 1, wn = wid & 1;
    f32x4 acc[4][4] = {};
    const int l8 = lane >> 3;
    const int c8 = (lane & 7) * 8;

    for (int k0 = ks * (E_ / KS_); k0 < (ks + 1) * (E_ / KS_); k0 += BK){
        #pragma unroll
        for (int i = 0; i < 4; ++i){
            const int R0 = wid * 32 + i * 8;
            gld16(A + (size_t)(row0 + R0 + l8) * E_ + k0 + c8, As + R0 * BK);
            gld16(Bm + (size_t)(R0 + l8) * E_ + k0 + c8, Bs + R0 * BK);
        }
        __syncthreads();
        #pragma unroll
        for (int kk = 0; kk < 2; ++kk){
            bf16x8 af[4], bfr[4];
            const int krow = lane & 15;
            const int kcol = kk * 32 + (lane >> 4) * 8;
            #pragma unroll
            for (int mi = 0; mi < 4; ++mi)
                af[mi] = *(const bf16x8*)(As + (wm*64 + mi*16 + krow) * BK + kcol);
            #pragma unroll
            for (int ni = 0; ni < 4; ++ni)
                bfr[ni] = *(const bf16x8*)(Bs + (wn*64 + ni*16 + krow) * BK + kcol);
            #pragma unroll
            for (int mi = 0; mi < 4; ++mi)
                #pragma unroll
                for (int ni = 0; ni < 4; ++ni)
                    acc[mi][ni] = __builtin_amdgcn_mfma_f32_16x16x32_bf16(af[mi], bfr[ni], acc[mi][ni], 0, 0, 0);
        }
        __syncthreads();
    }
    float* dst = part + (size_t)ks * M_ * 128;
    #pragma unroll
    for (int mi = 0; mi < 4; ++mi)
        #pragma unroll
        for (int ni = 0; ni < 4; ++ni)
            #pragma unroll
            for (int j = 0; j < 4; ++j){
                int r = row0 + wm*64 + mi*16 + (lane >> 4) * 4 + j;
                int c = wn*64 + ni*16 + (lane & 15);
                dst[(size_t)r * 128 + c] = acc[mi][ni][j];
            }
}

__global__ __launch_bounds__(256) void c96_reduce_k(const float* __restrict__ part,
                                                    ushort* __restrict__ C96){
    int i4 = blockIdx.x * 256 + threadIdx.x;     // over M_*128/4
    float4 a = *(const float4*)(part + (size_t)i4 * 4);
    #pragma unroll
    for (int k = 1; k < KS_; ++k){
        float4 b = *(const float4*)(part + (size_t)k * M_ * 128 + (size_t)i4 * 4);
        a.x += b.x; a.y += b.y; a.z += b.z; a.w += b.w;
    }
    ushort4 o;
    o.x = f2bf(a.x); o.y = f2bf(a.y); o.z = f2bf(a.z); o.w = f2bf(a.w);
    *(ushort4*)(C96 + (size_t)i4 * 4) = o;
}

// ---------------- causal depthwise conv1d + silu -> bf16 only ----------------
__global__ __launch_bounds__(256) void conv_silu_k(const ushort* __restrict__ xpre,
                                                   const float* __restrict__ conv_w,
                                                   const float* __restrict__ conv_b,
                                                   ushort* __restrict__ xb){
    int i4 = blockIdx.x * 256 + threadIdx.x;
    if (i4 >= M_ * E_ / 4) return;
    int idx = i4 * 4;
    int e = idx & (E_ - 1);
    int bl = idx >> 11;
    int t = bl & (L_ - 1);
    float acc[4];
    #pragma unroll
    for (int j = 0; j < 4; ++j) acc[j] = conv_b[e + j];
    #pragma unroll
    for (int k = 0; k < 4; ++k){
        int dt = 3 - k;
        if (t >= dt){
            ushort4 xv = *(const ushort4*)(xpre + idx - dt * E_);
            acc[0] += bf2f(xv.x) * conv_w[(e+0)*4 + k];
            acc[1] += bf2f(xv.y) * conv_w[(e+1)*4 + k];
            acc[2] += bf2f(xv.z) * conv_w[(e+2)*4 + k];
            acc[3] += bf2f(xv.w) * conv_w[(e+3)*4 + k];
        }
    }
    ushort4 sb;
    #pragma unroll
    for (int j = 0; j < 4; ++j){
        float s = acc[j] / (1.f + __expf(-acc[j]));
        ((ushort*)&sb)[j] = f2bf(s);
    }
    *(ushort4*)(xb + idx) = sb;
}

// ---------------- chunk-parallel selective scan, delta fused via MFMA ----------------
// delta[t,e] = softplus(dot64(xr[t,:], wd2[e,:]) + wd2_b[e]); xr = C96 cols 0..63.
// x is bf16 (xb) -- consistent with C96/B/C which already carry bf16 x.
// sdx = dt*x precomputed by the delta-producer lanes (removes 16x-redundant mul).
#define SLDF 68   // float tile stride (272B, 16B-aligned)
#define SLDH 72   // ushort tile stride (144B, 16B-aligned)
#define SYD 20    // sy stride (80B): breaks 8-way conflict of stride-16

// grid (E_/16, SSEG, B_), block 256 = 16 e x 16 n
__global__ __launch_bounds__(256) void seg1_k(const ushort* __restrict__ xb,
                                              const ushort* __restrict__ C96,
                                              const ushort* __restrict__ wd2b,
                                              const float* __restrict__ wd2_bias,
                                              const float* __restrict__ A_log,
                                              float* __restrict__ F,
                                              float* __restrict__ segdt){
    const int b = blockIdx.z, s = blockIdx.y, e0 = blockIdx.x * 16;
    const int tid = threadIdx.x;
    const int lane = tid & 63, wid = tid >> 6;
    const int n = tid & 15, ei = tid >> 4;
    const int e = e0 + ei;
    const float Aen = -__expf(A_log[e * N_ + n]);
    float h = 0.f, sdt = 0.f;
    __shared__ __align__(16) ushort sxr[64][SLDH];
    __shared__ __align__(16) ushort swd2[16][SLDH];
    __shared__ __align__(16) ushort sxu[16][SLDH];
    __shared__ float sd[16][SLDF], sdx[16][SLDF], sB[16][SLDF];
    const int tq = tid >> 2, qc = tid & 3;

    if (tid < 128){
        int r = tid >> 3, cc = (tid & 7) * 8;
        *(uint4*)&swd2[r][cc] = *(const uint4*)(wd2b + (size_t)(e0 + r) * DR_ + cc);
    }
    const float bias = wd2_bias[e0 + (lane & 15)];

    for (int c = 0; c < LSEG / 64; ++c){
        int t0 = s * LSEG + c * 64;
        size_t row = (size_t)(b * L_ + t0 + tq);
        *(uint4*)&sxr[tq][qc * 16]     = *(const uint4*)(C96 + row * 128 + qc * 16);
        *(uint4*)&sxr[tq][qc * 16 + 8] = *(const uint4*)(C96 + row * 128 + qc * 16 + 8);
        ushort4 rB = *(const ushort4*)(C96 + row * 128 + 64 + qc * 4);
        ushort4 xu = *(const ushort4*)(xb + row * E_ + e0 + qc * 4);
        sB[qc*4+0][tq] = bf2f(rB.x); sB[qc*4+1][tq] = bf2f(rB.y);
        sB[qc*4+2][tq] = bf2f(rB.z); sB[qc*4+3][tq] = bf2f(rB.w);
        sxu[qc*4+0][tq] = xu.x; sxu[qc*4+1][tq] = xu.y;
        sxu[qc*4+2][tq] = xu.z; sxu[qc*4+3][tq] = xu.w;
        __syncthreads();
        // fused delta: wave wid computes t rows wid*16..+15 x 16 e's
        f32x4 dacc = {};
        #pragma unroll
        for (int kk = 0; kk < 2; ++kk){
            bf16x8 af = *(const bf16x8*)&sxr[wid*16 + (lane & 15)][kk*32 + (lane >> 4)*8];
            bf16x8 bf = *(const bf16x8*)&swd2[lane & 15][kk*32 + (lane >> 4)*8];
            dacc = __builtin_amdgcn_mfma_f32_16x16x32_bf16(af, bf, dacc, 0, 0, 0);
        }
        {
            const int crow = lane & 15;
            const int ttc = wid*16 + (lane >> 4)*4;
            float4 dv;
            dv.x = softplus_f(dacc[0] + bias);
            dv.y = softplus_f(dacc[1] + bias);
            dv.z = softplus_f(dacc[2] + bias);
            dv.w = softplus_f(dacc[3] + bias);
            *(float4*)&sd[crow][ttc] = dv;
            ushort4 xu4 = *(const ushort4*)&sxu[crow][ttc];
            float4 dxv;
            dxv.x = dv.x * bf2f(xu4.x); dxv.y = dv.y * bf2f(xu4.y);
            dxv.z = dv.z * bf2f(xu4.z); dxv.w = dv.w * bf2f(xu4.w);
            *(float4*)&sdx[crow][ttc] = dxv;
        }
        __syncthreads();
        #pragma unroll
        for (int t = 0; t < 64; t += 4){
            float4 d4  = *(const float4*)&sd[ei][t];
            float4 dx4 = *(const float4*)&sdx[ei][t];
            float4 b4  = *(const float4*)&sB[n][t];
            h = __expf(d4.x*Aen)*h + dx4.x*b4.x;
            h = __expf(d4.y*Aen)*h + dx4.y*b4.y;
            h = __expf(d4.z*Aen)*h + dx4.z*b4.z;
            h = __expf(d4.w*Aen)*h + dx4.w*b4.w;
            sdt += d4.x + d4.y + d4.z + d4.w;
        }
        __syncthreads();
    }
    size_t base = ((size_t)(b * SSEG + s) * E_ + e) * N_ + n;
    F[base] = h;
    if (n == 0) segdt[(size_t)(b * SSEG + s) * E_ + e] = sdt;
}

// sequential carry over SSEG segments per (b,e,n)
__global__ __launch_bounds__(256) void carry_k(const float* __restrict__ F,
                                               const float* __restrict__ segdt,
                                               const float* __restrict__ A_log,
                                               float* __restrict__ carr){
    int idx = blockIdx.x * 256 + threadIdx.x;
    int n = idx & 15;
    int e = (idx >> 4) & (E_ - 1);
    int b = idx >> 15;
    const float Aen = -__expf(A_log[e * N_ + n]);
    float c = 0.f;
    #pragma unroll
    for (int s = 0; s < SSEG; ++s){
        size_t base = ((size_t)(b * SSEG + s) * E_ + e) * N_ + n;
        carr[base] = c;
        float P = __expf(Aen * segdt[(size_t)(b * SSEG + s) * E_ + e]);
        c = P * c + F[base];
    }
}

// grid (E_/16, SSEG, B_), block 256; gate fused into store
__global__ __launch_bounds__(256) void seg2_k(const ushort* __restrict__ xb,
                                              const ushort* __restrict__ C96,
                                              const ushort* __restrict__ wd2b,
                                              const float* __restrict__ wd2_bias,
                                              const float* __restrict__ A_log,
                                              const float* __restrict__ carr,
                                              const ushort* __restrict__ skipb,
                                              const float* __restrict__ W_D,
                                              ushort* __restrict__ y2){
    const int b = blockIdx.z, s = blockIdx.y, e0 = blockIdx.x * 16;
    const int tid = threadIdx.x;
    const int lane = tid & 63, wid = tid >> 6;
    const int n = tid & 15, ei = tid >> 4;
    const int e = e0 + ei;
    const float Aen = -__expf(A_log[e * N_ + n]);
    float h = carr[((size_t)(b * SSEG + s) * E_ + e) * N_ + n];
    __shared__ __align__(16) ushort sxr[64][SLDH];
    __shared__ __align__(16) ushort swd2[16][SLDH];
    __shared__ __align__(16) ushort sxu[16][SLDH];
    __shared__ float sd[16][SLDF], sdx[16][SLDF], sB[16][SLDF], sC[16][SLDF];
    __shared__ float sy[64][SYD];
    const int tq = tid >> 2, qc = tid & 3;

    if (tid < 128){
        int r = tid >> 3, cc = (tid & 7) * 8;
        *(uint4*)&swd2[r][cc] = *(const uint4*)(wd2b + (size_t)(e0 + r) * DR_ + cc);
    }
    const float bias = wd2_bias[e0 + (lane & 15)];
    const float4 wv = *(const float4*)(W_D + e0 + qc * 4);

    for (int c = 0; c < LSEG / 64; ++c){
        int t0 = s * LSEG + c * 64;
        size_t row = (size_t)(b * L_ + t0 + tq);
        *(uint4*)&sxr[tq][qc * 16]     = *(const uint4*)(C96 + row * 128 + qc * 16);
        *(uint4*)&sxr[tq][qc * 16 + 8] = *(const uint4*)(C96 + row * 128 + qc * 16 + 8);
        ushort4 rB = *(const ushort4*)(C96 + row * 128 + 64 + qc * 4);
        ushort4 rC = *(const ushort4*)(C96 + row * 128 + 80 + qc * 4);
        ushort4 xu = *(const ushort4*)(xb + row * E_ + e0 + qc * 4);
        sB[qc*4+0][tq] = bf2f(rB.x); sB[qc*4+1][tq] = bf2f(rB.y);
        sB[qc*4+2][tq] = bf2f(rB.z); sB[qc*4+3][tq] = bf2f(rB.w);
        sC[qc*4+0][tq] = bf2f(rC.x); sC[qc*4+1][tq] = bf2f(rC.y);
        sC[qc*4+2][tq] = bf2f(rC.z); sC[qc*4+3][tq] = bf2f(rC.w);
        sxu[qc*4+0][tq] = xu.x; sxu[qc*4+1][tq] = xu.y;
        sxu[qc*4+2][tq] = xu.z; sxu[qc*4+3][tq] = xu.w;
        __syncthreads();
        f32x4 dacc = {};
        #pragma unroll
        for (int kk = 0; kk < 2; ++kk){
            bf16x8 af = *(const bf16x8*)&sxr[wid*16 + (lane & 15)][kk*32 + (lane >> 4)*8];
            bf16x8 bf = *(const bf16x8*)&swd2[lane & 15][kk*32 + (lane >> 4)*8];
            dacc = __builtin_amdgcn_mfma_f32_16x16x32_bf16(af, bf, dacc, 0, 0, 0);
        }
        {
            const int crow = lane & 15;
            const int ttc = wid*16 + (lane >> 4)*4;
            float4 dv;
            dv.x = softplus_f(dacc[0] + bias);
            dv.y = softplus_f(dacc[1] + bias);
            dv.z = softplus_f(dacc[2] + bias);
            dv.w = softplus_f(dacc[3] + bias);
            *(float4*)&sd[crow][ttc] = dv;
            ushort4 xu4 = *(const ushort4*)&sxu[crow][ttc];
            float4 dxv;
            dxv.x = dv.x * bf2f(xu4.x); dxv.y = dv.y * bf2f(xu4.y);
            dxv.z = dv.z * bf2f(xu4.z); dxv.w = dv.w * bf2f(xu4.w);
            *(float4*)&sdx[crow][ttc] = dxv;
        }
        __syncthreads();
        #pragma unroll
        for (int t = 0; t < 64; t += 4){
            float4 d4  = *(const float4*)&sd[ei][t];
            float4 dx4 = *(const float4*)&sdx[ei][t];
            float4 b4  = *(const float4*)&sB[n][t];
            float4 c4  = *(const float4*)&sC[n][t];
            float y0, y1, y2v, y3;
            h = __expf(d4.x*Aen)*h + dx4.x*b4.x;  y0 = h * c4.x;
            h = __expf(d4.y*Aen)*h + dx4.y*b4.y;  y1 = h * c4.y;
            h = __expf(d4.z*Aen)*h + dx4.z*b4.z;  y2v = h * c4.z;
            h = __expf(d4.w*Aen)*h + dx4.w*b4.w;  y3 = h * c4.w;
            // 4-value 16-lane butterfly reduce: 5 shfls
            float s01 = (n & 1) ? y0 : y1;
            float r01 = __shfl_xor(s01, 1);
            float s23 = (n & 1) ? y2v : y3;
            float r23 = __shfl_xor(s23, 1);
            float va, vb;
            if (n & 1){ va = y1 + r01; vb = y3 + r23; }
            else      { va = y0 + r01; vb = y2v + r23; }
            float s2 = (n & 2) ? va : vb;
            float r2 = __shfl_xor(s2, 2);
            float v = ((n & 2) ? vb : va) + r2;
            v += __shfl_xor(v, 4);
            v += __shfl_xor(v, 8);
            if (n < 4) sy[t + n][ei] = v;
        }
        __syncthreads();
        {
            // fused gate: y2 = (y + W_D*x) * silu(skip) -> bf16
            size_t orow = (size_t)(b * L_ + t0 + tq);
            float4 yv = *(float4*)&sy[tq][qc * 4];
            float xs0 = bf2f(sxu[qc*4+0][tq]), xs1 = bf2f(sxu[qc*4+1][tq]);
            float xs2 = bf2f(sxu[qc*4+2][tq]), xs3 = bf2f(sxu[qc*4+3][tq]);
            ushort4 sv = *(const ushort4*)(skipb + orow * E_ + e0 + qc * 4);
            float sk0 = bf2f(sv.x), sk1 = bf2f(sv.y), sk2 = bf2f(sv.z), sk3 = bf2f(sv.w);
            ushort4 o;
            o.x = f2bf((yv.x + wv.x * xs0) * (sk0 / (1.f + __expf(-sk0))));
            o.y = f2bf((yv.y + wv.y * xs1) * (sk1 / (1.f + __expf(-sk1))));
            o.z = f2bf((yv.z + wv.z * xs2) * (sk2 / (1.f + __expf(-sk2))));
            o.w = f2bf((yv.w + wv.w * xs3) * (sk3 / (1.f + __expf(-sk3))));
            *(ushort4*)(y2 + orow * E_ + e0 + qc * 4) = o;
        }
        __syncthreads();
    }
}

// ---------------- launch ----------------
extern "C" void kernel_launch(void* const* d_in, const int* in_sizes, int n_in,
                              void* d_out, int out_size, void* d_ws, size_t ws_size,
                              hipStream_t stream){
    const float* resid  = (const float*)d_in[0];
    const float* norm_w = (const float*)d_in[1];
    const float* skip_w = (const float*)d_in[2];
    const float* in_w   = (const float*)d_in[3];
    const float* conv_w = (const float*)d_in[4];
    const float* conv_b = (const float*)d_in[5];
    const float* wd1    = (const float*)d_in[6];
    const float* wd2    = (const float*)d_in[7];
    const float* wd2_b  = (const float*)d_in[8];
    const float* wB     = (const float*)d_in[9];
    const float* wC     = (const float*)d_in[10];
    const float* A_log  = (const float*)d_in[11];
    const float* W_D    = (const float*)d_in[12];
    const float* out_w  = (const float*)d_in[13];
    float* out = (float*)d_out;

    char* ws = (char*)d_ws;
    size_t off = 0;
    auto alloc = [&](size_t bytes) -> char* {
        char* p = ws + off;
        off += (bytes + 255) & ~(size_t)255;
        return p;
    };
    // --- aliased region: wis (8MB) + xn (8MB) dead before the C96 GEMM runs;
    //     split-K partial buffer (16MB f32) reuses them.
    char* alias_base = ws;
    ushort* wis_b   = (ushort*)alloc((size_t)2 * E_ * D_ * 2);  // 8MB stacked [in_w; skip_w]
    ushort* xn_b    = (ushort*)alloc((size_t)M_ * D_ * 2);      // 8MB
    ushort* xpre_b  = (ushort*)alloc((size_t)M_ * E_ * 2);      // 16MB
    float*  part_buf= (float*)alias_base;                       // 16MB alias (KS_*M_*128*4)
    // --- persistent buffers
    ushort* wo_b    = (ushort*)alloc((size_t)D_ * E_ * 2);       // 4MB
    ushort* wd2_bf  = (ushort*)alloc((size_t)E_ * DR_ * 2);      // 256KB
    ushort* W96_b   = (ushort*)alloc((size_t)128 * E_ * 2);      // 512KB
    ushort* skip_b  = (ushort*)alloc((size_t)M_ * E_ * 2);       // 16MB
    ushort* xb_b    = (ushort*)alloc((size_t)M_ * E_ * 2);       // 16MB
    ushort* C96_b   = (ushort*)alloc((size_t)M_ * 128 * 2);      // 1MB
    float*  scr     = (float*)alloc((size_t)9 * 1024 * 1024);    // 9MB scratch
    ushort* y2_b    = (ushort*)alloc((size_t)M_ * E_ * 2);       // 16MB
    // sub-layout of scr: F (4MB) | carr (4MB) | segdt (256KB)
    float* F_buf    = scr;
    float* carr_buf = scr + (size_t)B_ * SSEG * E_ * N_;
    float* segdt_buf= scr + (size_t)2 * B_ * SSEG * E_ * N_;
    (void)ws_size; (void)in_sizes; (void)n_in; (void)out_size;

    const int thr = 256;
    auto blocks4 = [](int n){ return (n/4 + 255) / 256; };

    // weight conversions
    cvt4_k<<<blocks4(E_*D_), thr, 0, stream>>>(in_w,   wis_b,            E_*D_/4);
    cvt4_k<<<blocks4(E_*D_), thr, 0, stream>>>(skip_w, wis_b + (size_t)E_*D_, E_*D_/4);
    cvt4_k<<<blocks4(D_*E_), thr, 0, stream>>>(out_w,  wo_b,   D_*E_/4);
    cvt4_k<<<blocks4(E_*DR_), thr, 0, stream>>>(wd2,   wd2_bf, E_*DR_/4);
    cvt4_k<<<blocks4(DR_*E_), thr, 0, stream>>>(wd1,   W96_b,            DR_*E_/4);
    cvt4_k<<<blocks4(N_*E_),  thr, 0, stream>>>(wB,    W96_b + 64*E_,    N_*E_/4);
    cvt4_k<<<blocks4(N_*E_),  thr, 0, stream>>>(wC,    W96_b + 80*E_,    N_*E_/4);
    zero16_k<<<(32*E_ + 255)/256, thr, 0, stream>>>(W96_b + 96*E_, 32*E_);

    // RMSNorm
    rmsnorm_k<<<M_, thr, 0, stream>>>(resid, norm_w, xn_b);

    // fused in-proj + skip-proj: [4096,4096] = [4096,1024] x [4096,1024]^T
    gemm_dual_k<<<dim3(2*E_/BN, M_/BM), thr, 0, stream>>>(xn_b, wis_b, xpre_b, skip_b);

    // conv + silu -> bf16
    conv_silu_k<<<(M_*E_/4 + 255)/256, thr, 0, stream>>>(xpre_b, conv_w, conv_b, xb_b);

    // C96[4096,128] = x[4096,2048] x W96[128,2048]^T, split-K x8 + reduce
    gemm_c96_sk<<<dim3(KS_, M_/BM), thr, 0, stream>>>(xb_b, W96_b, part_buf);
    c96_reduce_k<<<(M_*128/4)/256, thr, 0, stream>>>(part_buf, C96_b);

    // chunk-parallel selective scan with fused delta; gate fused into seg2
    seg1_k<<<dim3(E_/16, SSEG, B_), thr, 0, stream>>>(xb_b, C96_b, wd2_bf, wd2_b, A_log, F_buf, segdt_buf);
    carry_k<<<(B_*E_*N_)/256, thr, 0, stream>>>(F_buf, segdt_buf, A_log, carr_buf);
    seg2_k<<<dim3(E_/16, SSEG, B_), thr, 0, stream>>>(xb_b, C96_b, wd2_bf, wd2_b, A_log, carr_buf,
                                                      skip_b, W_D, y2_b);

    // out-proj + residual: out[4096,1024] = y2[4096,2048] x out_w[1024,2048]^T + resid
    gemm_out_k<<<dim3(D_/BN, M_/BM), thr, 0, stream>>>(y2_b, wo_b, out, resid);
}

// Round 11
// 302.785 us; speedup vs baseline: 1.7427x; 1.0359x over previous
//
#include <hip/hip_runtime.h>
#include <hip/hip_bf16.h>

// Problem dims (fixed)
#define B_ 2
#define L_ 2048
#define D_ 1024
#define E_ 2048
#define N_ 16
#define DR_ 64
#define DC_ 4
#define M_ (B_*L_)   // 4096 rows
#define SSEG 16      // scan segments
#define LSEG (L_/SSEG)  // 128
#define KS_ 8        // split-K factor for C96 GEMM
#define CH 32        // scan chunk (timesteps per barrier group)

typedef __attribute__((ext_vector_type(8))) short bf16x8;
typedef __attribute__((ext_vector_type(4))) float f32x4;

__device__ __forceinline__ ushort f2bf(float x){
    union { float f; unsigned u; } v; v.f = x;
    unsigned r = v.u + 0x7FFFu + ((v.u >> 16) & 1u);
    return (ushort)(r >> 16);
}
__device__ __forceinline__ float bf2f(ushort u){
    union { unsigned u; float f; } v; v.u = ((unsigned)u) << 16;
    return v.f;
}
// fast softplus: __logf instead of library log1pf (error ~1e-9 abs, negligible)
__device__ __forceinline__ float softplus_f(float z){
    return (z > 20.f) ? z : __logf(1.f + __expf(z));
}

// async global->LDS, 16B per lane. LDS dest = wave-uniform base + lane*16.
__device__ __forceinline__ void gld16(const void* g, void* l){
    __builtin_amdgcn_global_load_lds(
        (const __attribute__((address_space(1))) unsigned int*)g,
        (__attribute__((address_space(3))) unsigned int*)l,
        16, 0, 0);
}

// ---------------- convert f32 -> bf16 (vec4) ----------------
__global__ void cvt4_k(const float* __restrict__ in, ushort* __restrict__ out, int n4){
    int i = blockIdx.x * 256 + threadIdx.x;
    if (i < n4){
        float4 v = ((const float4*)in)[i];
        ushort4 o;
        o.x = f2bf(v.x); o.y = f2bf(v.y); o.z = f2bf(v.z); o.w = f2bf(v.w);
        ((ushort4*)out)[i] = o;
    }
}

__global__ void zero16_k(ushort* __restrict__ p, int n){
    int i = blockIdx.x * 256 + threadIdx.x;
    if (i < n) p[i] = 0;
}

// ---------------- RMSNorm -> bf16 ----------------
__global__ __launch_bounds__(256) void rmsnorm_k(const float* __restrict__ resid,
                                                 const float* __restrict__ norm_w,
                                                 ushort* __restrict__ xn){
    int row = blockIdx.x;
    const float4* r = (const float4*)(resid + (size_t)row * D_);
    float4 v = r[threadIdx.x];
    float ss = v.x*v.x + v.y*v.y + v.z*v.z + v.w*v.w;
    for (int m = 32; m; m >>= 1) ss += __shfl_xor(ss, m);
    __shared__ float sred[4];
    if ((threadIdx.x & 63) == 0) sred[threadIdx.x >> 6] = ss;
    __syncthreads();
    float tot = sred[0] + sred[1] + sred[2] + sred[3];
    float scale = rsqrtf(tot / (float)D_ + 1e-5f);
    const float4* wv = (const float4*)norm_w;
    float4 w = wv[threadIdx.x];
    ushort4 o;
    o.x = f2bf(v.x * scale * w.x);
    o.y = f2bf(v.y * scale * w.y);
    o.z = f2bf(v.z * scale * w.z);
    o.w = f2bf(v.w * scale * w.w);
    ((ushort4*)(xn + (size_t)row * D_))[threadIdx.x] = o;
}

// ---------------- GEMM machinery (m97 structure, global_load_lds staging) ----------------
#define BM 128
#define BN 128
#define BK 64

// fused in-proj + skip-proj: Bm = [in_w ; skip_w] stacked (N = 2*E_),
// cols < E_ -> P1 (xpre), cols >= E_ -> P2 (skip). bf16 store.
// 1D grid (1024 blocks) with bijective XCD swizzle for L2 panel locality.
__global__ __launch_bounds__(256)
void gemm_dual_k(const ushort* __restrict__ A, const ushort* __restrict__ Bm,
                 ushort* __restrict__ P1, ushort* __restrict__ P2){
    __shared__ __align__(16) ushort As[BM * BK];
    __shared__ __align__(16) ushort Bs[BN * BK];
    const int wid9 = (blockIdx.x & 7) * 128 + (blockIdx.x >> 3);  // nwg=1024, bijective
    const int col0 = (wid9 & 31) * BN;
    const int row0 = (wid9 >> 5) * BM;
    const int tid = threadIdx.x;
    const int lane = tid & 63;
    const int wid = tid >> 6;
    const int wm = wid >> 1, wn = wid & 1;
    f32x4 acc[4][4] = {};
    const int l8 = lane >> 3;
    const int c8 = (lane & 7) * 8;

    for (int k0 = 0; k0 < D_; k0 += BK){
        #pragma unroll
        for (int i = 0; i < 4; ++i){
            const int R0 = wid * 32 + i * 8;
            gld16(A + (size_t)(row0 + R0 + l8) * D_ + k0 + c8, As + R0 * BK);
            gld16(Bm + (size_t)(col0 + R0 + l8) * D_ + k0 + c8, Bs + R0 * BK);
        }
        __syncthreads();
        #pragma unroll
        for (int kk = 0; kk < 2; ++kk){
            bf16x8 af[4], bfr[4];
            const int krow = lane & 15;
            const int kcol = kk * 32 + (lane >> 4) * 8;
            #pragma unroll
            for (int mi = 0; mi < 4; ++mi)
                af[mi] = *(const bf16x8*)(As + (wm*64 + mi*16 + krow) * BK + kcol);
            #pragma unroll
            for (int ni = 0; ni < 4; ++ni)
                bfr[ni] = *(const bf16x8*)(Bs + (wn*64 + ni*16 + krow) * BK + kcol);
            #pragma unroll
            for (int mi = 0; mi < 4; ++mi)
                #pragma unroll
                for (int ni = 0; ni < 4; ++ni)
                    acc[mi][ni] = __builtin_amdgcn_mfma_f32_16x16x32_bf16(af[mi], bfr[ni], acc[mi][ni], 0, 0, 0);
        }
        __syncthreads();
    }
    ushort* base = (col0 < E_) ? P1 : P2;
    const int cb = (col0 < E_) ? col0 : col0 - E_;
    #pragma unroll
    for (int mi = 0; mi < 4; ++mi)
        #pragma unroll
        for (int ni = 0; ni < 4; ++ni)
            #pragma unroll
            for (int j = 0; j < 4; ++j){
                int r = row0 + wm*64 + mi*16 + (lane >> 4) * 4 + j;
                int c = cb + wn*64 + ni*16 + (lane & 15);
                base[(size_t)r * E_ + c] = f2bf(acc[mi][ni][j]);
            }
}

// out-proj: C[M,N] f32 = A x B^T + aux (residual); 1D grid (256) with XCD swizzle
__global__ __launch_bounds__(256)
void gemm_out_k(const ushort* __restrict__ A, const ushort* __restrict__ Bm,
                float* __restrict__ Cp, const float* __restrict__ aux){
    __shared__ __align__(16) ushort As[BM * BK];
    __shared__ __align__(16) ushort Bs[BN * BK];
    const int wid9 = (blockIdx.x & 7) * 32 + (blockIdx.x >> 3);  // nwg=256, bijective
    const int col0 = (wid9 & 7) * BN;
    const int row0 = (wid9 >> 3) * BM;
    const int tid = threadIdx.x;
    const int lane = tid & 63;
    const int wid = tid >> 6;
    const int wm = wid >> 1, wn = wid & 1;
    f32x4 acc[4][4] = {};
    const int l8 = lane >> 3;
    const int c8 = (lane & 7) * 8;

    for (int k0 = 0; k0 < E_; k0 += BK){
        #pragma unroll
        for (int i = 0; i < 4; ++i){
            const int R0 = wid * 32 + i * 8;
            gld16(A + (size_t)(row0 + R0 + l8) * E_ + k0 + c8, As + R0 * BK);
            gld16(Bm + (size_t)(col0 + R0 + l8) * E_ + k0 + c8, Bs + R0 * BK);
        }
        __syncthreads();
        #pragma unroll
        for (int kk = 0; kk < 2; ++kk){
            bf16x8 af[4], bfr[4];
            const int krow = lane & 15;
            const int kcol = kk * 32 + (lane >> 4) * 8;
            #pragma unroll
            for (int mi = 0; mi < 4; ++mi)
                af[mi] = *(const bf16x8*)(As + (wm*64 + mi*16 + krow) * BK + kcol);
            #pragma unroll
            for (int ni = 0; ni < 4; ++ni)
                bfr[ni] = *(const bf16x8*)(Bs + (wn*64 + ni*16 + krow) * BK + kcol);
            #pragma unroll
            for (int mi = 0; mi < 4; ++mi)
                #pragma unroll
                for (int ni = 0; ni < 4; ++ni)
                    acc[mi][ni] = __builtin_amdgcn_mfma_f32_16x16x32_bf16(af[mi], bfr[ni], acc[mi][ni], 0, 0, 0);
        }
        __syncthreads();
    }
    #pragma unroll
    for (int mi = 0; mi < 4; ++mi)
        #pragma unroll
        for (int ni = 0; ni < 4; ++ni)
            #pragma unroll
            for (int j = 0; j < 4; ++j){
                int r = row0 + wm*64 + mi*16 + (lane >> 4) * 4 + j;
                int c = col0 + wn*64 + ni*16 + (lane & 15);
                size_t idx = (size_t)r * D_ + c;
                Cp[idx] = acc[mi][ni][j] + aux[idx];
            }
}

// ---------------- C96 GEMM, split-K: part[ks][4096][128] f32 partials ----------------
__global__ __launch_bounds__(256)
void gemm_c96_sk(const ushort* __restrict__ A, const ushort* __restrict__ Bm,
                 float* __restrict__ part){
    __shared__ __align__(16) ushort As[BM * BK];
    __shared__ __align__(16) ushort Bs[BN * BK];
    const int ks = blockIdx.x;
    const int row0 = blockIdx.y * BM;
    const int tid = threadIdx.x;
    const int lane = tid & 63;
    const int wid = tid >> 6;
    const int wm = wid >> 1, wn = wid & 1;
    f32x4 acc[4][4] = {};
    const int l8 = lane >> 3;
    const int c8 = (lane & 7) * 8;

    for (int k0 = ks * (E_ / KS_); k0 < (ks + 1) * (E_ / KS_); k0 += BK){
        #pragma unroll
        for (int i = 0; i < 4; ++i){
            const int R0 = wid * 32 + i * 8;
            gld16(A + (size_t)(row0 + R0 + l8) * E_ + k0 + c8, As + R0 * BK);
            gld16(Bm + (size_t)(R0 + l8) * E_ + k0 + c8, Bs + R0 * BK);
        }
        __syncthreads();
        #pragma unroll
        for (int kk = 0; kk < 2; ++kk){
            bf16x8 af[4], bfr[4];
            const int krow = lane & 15;
            const int kcol = kk * 32 + (lane >> 4) * 8;
            #pragma unroll
            for (int mi = 0; mi < 4; ++mi)
                af[mi] = *(const bf16x8*)(As + (wm*64 + mi*16 + krow) * BK + kcol);
            #pragma unroll
            for (int ni = 0; ni < 4; ++ni)
                bfr[ni] = *(const bf16x8*)(Bs + (wn*64 + ni*16 + krow) * BK + kcol);
            #pragma unroll
            for (int mi = 0; mi < 4; ++mi)
                #pragma unroll
                for (int ni = 0; ni < 4; ++ni)
                    acc[mi][ni] = __builtin_amdgcn_mfma_f32_16x16x32_bf16(af[mi], bfr[ni], acc[mi][ni], 0, 0, 0);
        }
        __syncthreads();
    }
    float* dst = part + (size_t)ks * M_ * 128;
    #pragma unroll
    for (int mi = 0; mi < 4; ++mi)
        #pragma unroll
        for (int ni = 0; ni < 4; ++ni)
            #pragma unroll
            for (int j = 0; j < 4; ++j){
                int r = row0 + wm*64 + mi*16 + (lane >> 4) * 4 + j;
                int c = wn*64 + ni*16 + (lane & 15);
                dst[(size_t)r * 128 + c] = acc[mi][ni][j];
            }
}

__global__ __launch_bounds__(256) void c96_reduce_k(const float* __restrict__ part,
                                                    ushort* __restrict__ C96){
    int i4 = blockIdx.x * 256 + threadIdx.x;     // over M_*128/4
    float4 a = *(const float4*)(part + (size_t)i4 * 4);
    #pragma unroll
    for (int k = 1; k < KS_; ++k){
        float4 b = *(const float4*)(part + (size_t)k * M_ * 128 + (size_t)i4 * 4);
        a.x += b.x; a.y += b.y; a.z += b.z; a.w += b.w;
    }
    ushort4 o;
    o.x = f2bf(a.x); o.y = f2bf(a.y); o.z = f2bf(a.z); o.w = f2bf(a.w);
    *(ushort4*)(C96 + (size_t)i4 * 4) = o;
}

// ---------------- causal depthwise conv1d + silu -> bf16 only ----------------
__global__ __launch_bounds__(256) void conv_silu_k(const ushort* __restrict__ xpre,
                                                   const float* __restrict__ conv_w,
                                                   const float* __restrict__ conv_b,
                                                   ushort* __restrict__ xb){
    int i4 = blockIdx.x * 256 + threadIdx.x;
    if (i4 >= M_ * E_ / 4) return;
    int idx = i4 * 4;
    int e = idx & (E_ - 1);
    int bl = idx >> 11;
    int t = bl & (L_ - 1);
    float acc[4];
    #pragma unroll
    for (int j = 0; j < 4; ++j) acc[j] = conv_b[e + j];
    #pragma unroll
    for (int k = 0; k < 4; ++k){
        int dt = 3 - k;
        if (t >= dt){
            ushort4 xv = *(const ushort4*)(xpre + idx - dt * E_);
            acc[0] += bf2f(xv.x) * conv_w[(e+0)*4 + k];
            acc[1] += bf2f(xv.y) * conv_w[(e+1)*4 + k];
            acc[2] += bf2f(xv.z) * conv_w[(e+2)*4 + k];
            acc[3] += bf2f(xv.w) * conv_w[(e+3)*4 + k];
        }
    }
    ushort4 sb;
    #pragma unroll
    for (int j = 0; j < 4; ++j){
        float s = acc[j] / (1.f + __expf(-acc[j]));
        ((ushort*)&sb)[j] = f2bf(s);
    }
    *(ushort4*)(xb + idx) = sb;
}

// ---------------- chunk-parallel selective scan, delta fused via MFMA ----------------
// CH=32 chunks: LDS ~20KB -> 8 blocks/CU (was 36KB -> 4). VGPR 52 <= 64 so
// __launch_bounds__(256,8) holds 8 waves/SIMD (r10 was latency-bound at 40% occ).
#define SF2 36   // f32 tile stride (144B, 16B-aligned)
#define SYD 20   // sy stride

// grid (E_/16, SSEG, B_), block 256 = 16 e x 16 n
__global__ __launch_bounds__(256, 8) void seg1_k(const ushort* __restrict__ xb,
                                              const ushort* __restrict__ C96,
                                              const ushort* __restrict__ wd2b,
                                              const float* __restrict__ wd2_bias,
                                              const float* __restrict__ A_log,
                                              float* __restrict__ F,
                                              float* __restrict__ segdt){
    const int b = blockIdx.z, s = blockIdx.y, e0 = blockIdx.x * 16;
    const int tid = threadIdx.x;
    const int lane = tid & 63, wid = tid >> 6;
    const int n = tid & 15, ei = tid >> 4;
    const int e = e0 + ei;
    const float Aen = -__expf(A_log[e * N_ + n]);
    float h = 0.f, sdt = 0.f;
    __shared__ __align__(16) ushort sxr[CH][72];
    __shared__ __align__(16) ushort swd2[16][72];
    __shared__ __align__(16) ushort sxu[16][40];
    __shared__ float sd[16][SF2], sdx[16][SF2], sB[16][SF2];
    const int tq = tid >> 3, qc = tid & 7;   // row 0..31, col-group 0..7

    if (tid < 128){
        int r = tid >> 3, cc = (tid & 7) * 8;
        *(uint4*)&swd2[r][cc] = *(const uint4*)(wd2b + (size_t)(e0 + r) * DR_ + cc);
    }
    const float bias = wd2_bias[e0 + (lane & 15)];

    for (int c = 0; c < LSEG / CH; ++c){
        int t0 = s * LSEG + c * CH;
        size_t row = (size_t)(b * L_ + t0 + tq);
        *(uint4*)&sxr[tq][qc * 8] = *(const uint4*)(C96 + row * 128 + qc * 8);
        ushort2 rB = *(const ushort2*)(C96 + row * 128 + 64 + qc * 2);
        ushort2 xu = *(const ushort2*)(xb + row * E_ + e0 + qc * 2);
        sB[qc*2+0][tq] = bf2f(rB.x); sB[qc*2+1][tq] = bf2f(rB.y);
        sxu[qc*2+0][tq] = xu.x; sxu[qc*2+1][tq] = xu.y;
        __syncthreads();
        // fused delta: waves 0,1 each compute one 16-t x 16-e tile
        if (wid < 2){
            f32x4 dacc = {};
            #pragma unroll
            for (int kk = 0; kk < 2; ++kk){
                bf16x8 af = *(const bf16x8*)&sxr[wid*16 + (lane & 15)][kk*32 + (lane >> 4)*8];
                bf16x8 bf = *(const bf16x8*)&swd2[lane & 15][kk*32 + (lane >> 4)*8];
                dacc = __builtin_amdgcn_mfma_f32_16x16x32_bf16(af, bf, dacc, 0, 0, 0);
            }
            const int crow = lane & 15;
            const int ttc = wid*16 + (lane >> 4)*4;
            float4 dv;
            dv.x = softplus_f(dacc[0] + bias);
            dv.y = softplus_f(dacc[1] + bias);
            dv.z = softplus_f(dacc[2] + bias);
            dv.w = softplus_f(dacc[3] + bias);
            *(float4*)&sd[crow][ttc] = dv;
            ushort4 xu4 = *(const ushort4*)&sxu[crow][ttc];
            float4 dxv;
            dxv.x = dv.x * bf2f(xu4.x); dxv.y = dv.y * bf2f(xu4.y);
            dxv.z = dv.z * bf2f(xu4.z); dxv.w = dv.w * bf2f(xu4.w);
            *(float4*)&sdx[crow][ttc] = dxv;
        }
        __syncthreads();
        #pragma unroll
        for (int t = 0; t < CH; t += 4){
            float4 d4  = *(const float4*)&sd[ei][t];
            float4 dx4 = *(const float4*)&sdx[ei][t];
            float4 b4  = *(const float4*)&sB[n][t];
            h = __expf(d4.x*Aen)*h + dx4.x*b4.x;
            h = __expf(d4.y*Aen)*h + dx4.y*b4.y;
            h = __expf(d4.z*Aen)*h + dx4.z*b4.z;
            h = __expf(d4.w*Aen)*h + dx4.w*b4.w;
            sdt += d4.x + d4.y + d4.z + d4.w;
        }
        __syncthreads();
    }
    size_t base = ((size_t)(b * SSEG + s) * E_ + e) * N_ + n;
    F[base] = h;
    if (n == 0) segdt[(size_t)(b * SSEG + s) * E_ + e] = sdt;
}

// sequential carry over SSEG segments per (b,e,n)
__global__ __launch_bounds__(256) void carry_k(const float* __restrict__ F,
                                               const float* __restrict__ segdt,
                                               const float* __restrict__ A_log,
                                               float* __restrict__ carr){
    int idx = blockIdx.x * 256 + threadIdx.x;
    int n = idx & 15;
    int e = (idx >> 4) & (E_ - 1);
    int b = idx >> 15;
    const float Aen = -__expf(A_log[e * N_ + n]);
    float c = 0.f;
    #pragma unroll
    for (int s = 0; s < SSEG; ++s){
        size_t base = ((size_t)(b * SSEG + s) * E_ + e) * N_ + n;
        carr[base] = c;
        float P = __expf(Aen * segdt[(size_t)(b * SSEG + s) * E_ + e]);
        c = P * c + F[base];
    }
}

// grid (E_/16, SSEG, B_), block 256; gate fused into store
__global__ __launch_bounds__(256, 8) void seg2_k(const ushort* __restrict__ xb,
                                              const ushort* __restrict__ C96,
                                              const ushort* __restrict__ wd2b,
                                              const float* __restrict__ wd2_bias,
                                              const float* __restrict__ A_log,
                                              const float* __restrict__ carr,
                                              const ushort* __restrict__ skipb,
                                              const float* __restrict__ W_D,
                                              ushort* __restrict__ y2){
    const int b = blockIdx.z, s = blockIdx.y, e0 = blockIdx.x * 16;
    const int tid = threadIdx.x;
    const int lane = tid & 63, wid = tid >> 6;
    const int n = tid & 15, ei = tid >> 4;
    const int e = e0 + ei;
    const float Aen = -__expf(A_log[e * N_ + n]);
    float h = carr[((size_t)(b * SSEG + s) * E_ + e) * N_ + n];
    __shared__ __align__(16) ushort sxr[CH][72];
    __shared__ __align__(16) ushort swd2[16][72];
    __shared__ __align__(16) ushort sxu[16][40];
    __shared__ float sd[16][SF2], sdx[16][SF2], sB[16][SF2], sC[16][SF2];
    __shared__ float sy[CH][SYD];
    const int tq = tid >> 3, qc = tid & 7;

    if (tid < 128){
        int r = tid >> 3, cc = (tid & 7) * 8;
        *(uint4*)&swd2[r][cc] = *(const uint4*)(wd2b + (size_t)(e0 + r) * DR_ + cc);
    }
    const float bias = wd2_bias[e0 + (lane & 15)];
    const float wv0 = W_D[e0 + qc * 2], wv1 = W_D[e0 + qc * 2 + 1];

    for (int c = 0; c < LSEG / CH; ++c){
        int t0 = s * LSEG + c * CH;
        size_t row = (size_t)(b * L_ + t0 + tq);
        *(uint4*)&sxr[tq][qc * 8] = *(const uint4*)(C96 + row * 128 + qc * 8);
        ushort2 rB = *(const ushort2*)(C96 + row * 128 + 64 + qc * 2);
        ushort2 rC = *(const ushort2*)(C96 + row * 128 + 80 + qc * 2);
        ushort2 xu = *(const ushort2*)(xb + row * E_ + e0 + qc * 2);
        sB[qc*2+0][tq] = bf2f(rB.x); sB[qc*2+1][tq] = bf2f(rB.y);
        sC[qc*2+0][tq] = bf2f(rC.x); sC[qc*2+1][tq] = bf2f(rC.y);
        sxu[qc*2+0][tq] = xu.x; sxu[qc*2+1][tq] = xu.y;
        __syncthreads();
        if (wid < 2){
            f32x4 dacc = {};
            #pragma unroll
            for (int kk = 0; kk < 2; ++kk){
                bf16x8 af = *(const bf16x8*)&sxr[wid*16 + (lane & 15)][kk*32 + (lane >> 4)*8];
                bf16x8 bf = *(const bf16x8*)&swd2[lane & 15][kk*32 + (lane >> 4)*8];
                dacc = __builtin_amdgcn_mfma_f32_16x16x32_bf16(af, bf, dacc, 0, 0, 0);
            }
            const int crow = lane & 15;
            const int ttc = wid*16 + (lane >> 4)*4;
            float4 dv;
            dv.x = softplus_f(dacc[0] + bias);
            dv.y = softplus_f(dacc[1] + bias);
            dv.z = softplus_f(dacc[2] + bias);
            dv.w = softplus_f(dacc[3] + bias);
            *(float4*)&sd[crow][ttc] = dv;
            ushort4 xu4 = *(const ushort4*)&sxu[crow][ttc];
            float4 dxv;
            dxv.x = dv.x * bf2f(xu4.x); dxv.y = dv.y * bf2f(xu4.y);
            dxv.z = dv.z * bf2f(xu4.z); dxv.w = dv.w * bf2f(xu4.w);
            *(float4*)&sdx[crow][ttc] = dxv;
        }
        __syncthreads();
        #pragma unroll
        for (int t = 0; t < CH; t += 4){
            float4 d4  = *(const float4*)&sd[ei][t];
            float4 dx4 = *(const float4*)&sdx[ei][t];
            float4 b4  = *(const float4*)&sB[n][t];
            float4 c4  = *(const float4*)&sC[n][t];
            float y0, y1, y2v, y3;
            h = __expf(d4.x*Aen)*h + dx4.x*b4.x;  y0 = h * c4.x;
            h = __expf(d4.y*Aen)*h + dx4.y*b4.y;  y1 = h * c4.y;
            h = __expf(d4.z*Aen)*h + dx4.z*b4.z;  y2v = h * c4.z;
            h = __expf(d4.w*Aen)*h + dx4.w*b4.w;  y3 = h * c4.w;
            // 4-value 16-lane butterfly reduce: 5 shfls
            float s01 = (n & 1) ? y0 : y1;
            float r01 = __shfl_xor(s01, 1);
            float s23 = (n & 1) ? y2v : y3;
            float r23 = __shfl_xor(s23, 1);
            float va, vb;
            if (n & 1){ va = y1 + r01; vb = y3 + r23; }
            else      { va = y0 + r01; vb = y2v + r23; }
            float s2 = (n & 2) ? va : vb;
            float r2 = __shfl_xor(s2, 2);
            float v = ((n & 2) ? vb : va) + r2;
            v += __shfl_xor(v, 4);
            v += __shfl_xor(v, 8);
            if (n < 4) sy[t + n][ei] = v;
        }
        __syncthreads();
        {
            // fused gate: y2 = (y + W_D*x) * silu(skip) -> bf16
            size_t orow = (size_t)(b * L_ + t0 + tq);
            float yv0 = sy[tq][qc*2], yv1 = sy[tq][qc*2+1];
            float xs0 = bf2f(sxu[qc*2+0][tq]), xs1 = bf2f(sxu[qc*2+1][tq]);
            ushort2 sv = *(const ushort2*)(skipb + orow * E_ + e0 + qc * 2);
            float sk0 = bf2f(sv.x), sk1 = bf2f(sv.y);
            ushort2 o;
            o.x = f2bf((yv0 + wv0 * xs0) * (sk0 / (1.f + __expf(-sk0))));
            o.y = f2bf((yv1 + wv1 * xs1) * (sk1 / (1.f + __expf(-sk1))));
            *(ushort2*)(y2 + orow * E_ + e0 + qc * 2) = o;
        }
        __syncthreads();
    }
}

// ---------------- launch ----------------
extern "C" void kernel_launch(void* const* d_in, const int* in_sizes, int n_in,
                              void* d_out, int out_size, void* d_ws, size_t ws_size,
                              hipStream_t stream){
    const float* resid  = (const float*)d_in[0];
    const float* norm_w = (const float*)d_in[1];
    const float* skip_w = (const float*)d_in[2];
    const float* in_w   = (const float*)d_in[3];
    const float* conv_w = (const float*)d_in[4];
    const float* conv_b = (const float*)d_in[5];
    const float* wd1    = (const float*)d_in[6];
    const float* wd2    = (const float*)d_in[7];
    const float* wd2_b  = (const float*)d_in[8];
    const float* wB     = (const float*)d_in[9];
    const float* wC     = (const float*)d_in[10];
    const float* A_log  = (const float*)d_in[11];
    const float* W_D    = (const float*)d_in[12];
    const float* out_w  = (const float*)d_in[13];
    float* out = (float*)d_out;

    char* ws = (char*)d_ws;
    size_t off = 0;
    auto alloc = [&](size_t bytes) -> char* {
        char* p = ws + off;
        off += (bytes + 255) & ~(size_t)255;
        return p;
    };
    // --- aliased region: wis (8MB) + xn (8MB) dead before the C96 GEMM runs;
    //     split-K partial buffer (16MB f32) reuses them.
    char* alias_base = ws;
    ushort* wis_b   = (ushort*)alloc((size_t)2 * E_ * D_ * 2);  // 8MB stacked [in_w; skip_w]
    ushort* xn_b    = (ushort*)alloc((size_t)M_ * D_ * 2);      // 8MB
    ushort* xpre_b  = (ushort*)alloc((size_t)M_ * E_ * 2);      // 16MB
    float*  part_buf= (float*)alias_base;                       // 16MB alias (KS_*M_*128*4)
    // --- persistent buffers
    ushort* wo_b    = (ushort*)alloc((size_t)D_ * E_ * 2);       // 4MB
    ushort* wd2_bf  = (ushort*)alloc((size_t)E_ * DR_ * 2);      // 256KB
    ushort* W96_b   = (ushort*)alloc((size_t)128 * E_ * 2);      // 512KB
    ushort* skip_b  = (ushort*)alloc((size_t)M_ * E_ * 2);       // 16MB
    ushort* xb_b    = (ushort*)alloc((size_t)M_ * E_ * 2);       // 16MB
    ushort* C96_b   = (ushort*)alloc((size_t)M_ * 128 * 2);      // 1MB
    float*  scr     = (float*)alloc((size_t)9 * 1024 * 1024);    // 9MB scratch
    ushort* y2_b    = (ushort*)alloc((size_t)M_ * E_ * 2);       // 16MB
    // sub-layout of scr: F (4MB) | carr (4MB) | segdt (256KB)
    float* F_buf    = scr;
    float* carr_buf = scr + (size_t)B_ * SSEG * E_ * N_;
    float* segdt_buf= scr + (size_t)2 * B_ * SSEG * E_ * N_;
    (void)ws_size; (void)in_sizes; (void)n_in; (void)out_size;

    const int thr = 256;
    auto blocks4 = [](int n){ return (n/4 + 255) / 256; };

    // weight conversions
    cvt4_k<<<blocks4(E_*D_), thr, 0, stream>>>(in_w,   wis_b,            E_*D_/4);
    cvt4_k<<<blocks4(E_*D_), thr, 0, stream>>>(skip_w, wis_b + (size_t)E_*D_, E_*D_/4);
    cvt4_k<<<blocks4(D_*E_), thr, 0, stream>>>(out_w,  wo_b,   D_*E_/4);
    cvt4_k<<<blocks4(E_*DR_), thr, 0, stream>>>(wd2,   wd2_bf, E_*DR_/4);
    cvt4_k<<<blocks4(DR_*E_), thr, 0, stream>>>(wd1,   W96_b,            DR_*E_/4);
    cvt4_k<<<blocks4(N_*E_),  thr, 0, stream>>>(wB,    W96_b + 64*E_,    N_*E_/4);
    cvt4_k<<<blocks4(N_*E_),  thr, 0, stream>>>(wC,    W96_b + 80*E_,    N_*E_/4);
    zero16_k<<<(32*E_ + 255)/256, thr, 0, stream>>>(W96_b + 96*E_, 32*E_);

    // RMSNorm
    rmsnorm_k<<<M_, thr, 0, stream>>>(resid, norm_w, xn_b);

    // fused in-proj + skip-proj: [4096,4096] = [4096,1024] x [4096,1024]^T
    gemm_dual_k<<<1024, thr, 0, stream>>>(xn_b, wis_b, xpre_b, skip_b);

    // conv + silu -> bf16
    conv_silu_k<<<(M_*E_/4 + 255)/256, thr, 0, stream>>>(xpre_b, conv_w, conv_b, xb_b);

    // C96[4096,128] = x[4096,2048] x W96[128,2048]^T, split-K x8 + reduce
    gemm_c96_sk<<<dim3(KS_, M_/BM), thr, 0, stream>>>(xb_b, W96_b, part_buf);
    c96_reduce_k<<<(M_*128/4)/256, thr, 0, stream>>>(part_buf, C96_b);

    // chunk-parallel selective scan with fused delta; gate fused into seg2
    seg1_k<<<dim3(E_/16, SSEG, B_), thr, 0, stream>>>(xb_b, C96_b, wd2_bf, wd2_b, A_log, F_buf, segdt_buf);
    carry_k<<<(B_*E_*N_)/256, thr, 0, stream>>>(F_buf, segdt_buf, A_log, carr_buf);
    seg2_k<<<dim3(E_/16, SSEG, B_), thr, 0, stream>>>(xb_b, C96_b, wd2_bf, wd2_b, A_log, carr_buf,
                                                      skip_b, W_D, y2_b);

    // out-proj + residual: out[4096,1024] = y2[4096,2048] x out_w[1024,2048]^T + resid
    gemm_out_k<<<256, thr, 0, stream>>>(y2_b, wo_b, out, resid);
}

// Round 12
// 281.635 us; speedup vs baseline: 1.8735x; 1.0751x over previous
//
#include <hip/hip_runtime.h>
#include <hip/hip_bf16.h>

// Problem dims (fixed)
#define B_ 2
#define L_ 2048
#define D_ 1024
#define E_ 2048
#define N_ 16
#define DR_ 64
#define DC_ 4
#define M_ (B_*L_)   // 4096 rows
#define SSEG 16      // scan segments
#define LSEG (L_/SSEG)  // 128
#define KS_ 8        // split-K factor for C96 GEMM
#define CH 32        // scan chunk (timesteps per barrier group)

typedef __attribute__((ext_vector_type(8))) short bf16x8;
typedef __attribute__((ext_vector_type(4))) float f32x4;

__device__ __forceinline__ ushort f2bf(float x){
    union { float f; unsigned u; } v; v.f = x;
    unsigned r = v.u + 0x7FFFu + ((v.u >> 16) & 1u);
    return (ushort)(r >> 16);
}
__device__ __forceinline__ float bf2f(ushort u){
    union { unsigned u; float f; } v; v.u = ((unsigned)u) << 16;
    return v.f;
}
// fast softplus: __logf instead of library log1pf (error ~1e-9 abs, negligible)
__device__ __forceinline__ float softplus_f(float z){
    return (z > 20.f) ? z : __logf(1.f + __expf(z));
}

// async global->LDS, 16B per lane. LDS dest = wave-uniform base + lane*16.
__device__ __forceinline__ void gld16(const void* g, void* l){
    __builtin_amdgcn_global_load_lds(
        (const __attribute__((address_space(1))) unsigned int*)g,
        (__attribute__((address_space(3))) unsigned int*)l,
        16, 0, 0);
}

// ---------------- fused weight prep: all f32->bf16 conversions + zero-fill ----------------
// ranges in 4-element units
#define PR0 (E_*D_/4)            // in_w  -> wis[0]
#define PR1 (2*PR0)              // skip_w-> wis[E*D]
#define PR2 (3*PR0)              // out_w -> wo
#define PR3 (PR2 + E_*DR_/4)     // wd2   -> wd2b
#define PR4 (PR3 + DR_*E_/4)     // wd1   -> W96[0]
#define PR5 (PR4 + N_*E_/4)      // wB    -> W96[64E]
#define PR6 (PR5 + N_*E_/4)      // wC    -> W96[80E]
#define PR7 (PR6 + 32*E_/4)      // zero  -> W96[96E]
__global__ __launch_bounds__(256) void prep_k(const float* __restrict__ in_w,
                                              const float* __restrict__ skip_w,
                                              const float* __restrict__ out_w,
                                              const float* __restrict__ wd2,
                                              const float* __restrict__ wd1,
                                              const float* __restrict__ wB,
                                              const float* __restrict__ wC,
                                              ushort* __restrict__ wis,
                                              ushort* __restrict__ wo,
                                              ushort* __restrict__ wd2b,
                                              ushort* __restrict__ W96){
    int i = blockIdx.x * 256 + threadIdx.x;
    const float* src; ushort* dst; int off;
    if (i < PR0)      { src = in_w;   dst = wis;                       off = i; }
    else if (i < PR1) { src = skip_w; dst = wis + (size_t)E_*D_;       off = i - PR0; }
    else if (i < PR2) { src = out_w;  dst = wo;                        off = i - PR1; }
    else if (i < PR3) { src = wd2;    dst = wd2b;                      off = i - PR2; }
    else if (i < PR4) { src = wd1;    dst = W96;                       off = i - PR3; }
    else if (i < PR5) { src = wB;     dst = W96 + (size_t)64*E_;       off = i - PR4; }
    else if (i < PR6) { src = wC;     dst = W96 + (size_t)80*E_;       off = i - PR5; }
    else if (i < PR7) {
        ushort4 z = {0,0,0,0};
        ((ushort4*)(W96 + (size_t)96*E_))[i - PR6] = z;
        return;
    } else return;
    float4 v = ((const float4*)src)[off];
    ushort4 o;
    o.x = f2bf(v.x); o.y = f2bf(v.y); o.z = f2bf(v.z); o.w = f2bf(v.w);
    ((ushort4*)dst)[off] = o;
}

// ---------------- RMSNorm -> bf16 ----------------
__global__ __launch_bounds__(256) void rmsnorm_k(const float* __restrict__ resid,
                                                 const float* __restrict__ norm_w,
                                                 ushort* __restrict__ xn){
    int row = blockIdx.x;
    const float4* r = (const float4*)(resid + (size_t)row * D_);
    float4 v = r[threadIdx.x];
    float ss = v.x*v.x + v.y*v.y + v.z*v.z + v.w*v.w;
    for (int m = 32; m; m >>= 1) ss += __shfl_xor(ss, m);
    __shared__ float sred[4];
    if ((threadIdx.x & 63) == 0) sred[threadIdx.x >> 6] = ss;
    __syncthreads();
    float tot = sred[0] + sred[1] + sred[2] + sred[3];
    float scale = rsqrtf(tot / (float)D_ + 1e-5f);
    const float4* wv = (const float4*)norm_w;
    float4 w = wv[threadIdx.x];
    ushort4 o;
    o.x = f2bf(v.x * scale * w.x);
    o.y = f2bf(v.y * scale * w.y);
    o.z = f2bf(v.z * scale * w.z);
    o.w = f2bf(v.w * scale * w.w);
    ((ushort4*)(xn + (size_t)row * D_))[threadIdx.x] = o;
}

// ---------------- GEMM machinery (m97 structure, global_load_lds staging) ----------------
#define BM 128
#define BN 128
#define BK 64

// fused in-proj + skip-proj: Bm = [in_w ; skip_w] stacked (N = 2*E_),
// cols < E_ -> P1 (xpre), cols >= E_ -> P2 (skip). bf16 store.
// 1D grid (1024 blocks) with bijective XCD swizzle for L2 panel locality.
__global__ __launch_bounds__(256)
void gemm_dual_k(const ushort* __restrict__ A, const ushort* __restrict__ Bm,
                 ushort* __restrict__ P1, ushort* __restrict__ P2){
    __shared__ __align__(16) ushort As[BM * BK];
    __shared__ __align__(16) ushort Bs[BN * BK];
    const int wid9 = (blockIdx.x & 7) * 128 + (blockIdx.x >> 3);  // nwg=1024, bijective
    const int col0 = (wid9 & 31) * BN;
    const int row0 = (wid9 >> 5) * BM;
    const int tid = threadIdx.x;
    const int lane = tid & 63;
    const int wid = tid >> 6;
    const int wm = wid >> 1, wn = wid & 1;
    f32x4 acc[4][4] = {};
    const int l8 = lane >> 3;
    const int c8 = (lane & 7) * 8;

    for (int k0 = 0; k0 < D_; k0 += BK){
        #pragma unroll
        for (int i = 0; i < 4; ++i){
            const int R0 = wid * 32 + i * 8;
            gld16(A + (size_t)(row0 + R0 + l8) * D_ + k0 + c8, As + R0 * BK);
            gld16(Bm + (size_t)(col0 + R0 + l8) * D_ + k0 + c8, Bs + R0 * BK);
        }
        __syncthreads();
        #pragma unroll
        for (int kk = 0; kk < 2; ++kk){
            bf16x8 af[4], bfr[4];
            const int krow = lane & 15;
            const int kcol = kk * 32 + (lane >> 4) * 8;
            #pragma unroll
            for (int mi = 0; mi < 4; ++mi)
                af[mi] = *(const bf16x8*)(As + (wm*64 + mi*16 + krow) * BK + kcol);
            #pragma unroll
            for (int ni = 0; ni < 4; ++ni)
                bfr[ni] = *(const bf16x8*)(Bs + (wn*64 + ni*16 + krow) * BK + kcol);
            #pragma unroll
            for (int mi = 0; mi < 4; ++mi)
                #pragma unroll
                for (int ni = 0; ni < 4; ++ni)
                    acc[mi][ni] = __builtin_amdgcn_mfma_f32_16x16x32_bf16(af[mi], bfr[ni], acc[mi][ni], 0, 0, 0);
        }
        __syncthreads();
    }
    ushort* base = (col0 < E_) ? P1 : P2;
    const int cb = (col0 < E_) ? col0 : col0 - E_;
    #pragma unroll
    for (int mi = 0; mi < 4; ++mi)
        #pragma unroll
        for (int ni = 0; ni < 4; ++ni)
            #pragma unroll
            for (int j = 0; j < 4; ++j){
                int r = row0 + wm*64 + mi*16 + (lane >> 4) * 4 + j;
                int c = cb + wn*64 + ni*16 + (lane & 15);
                base[(size_t)r * E_ + c] = f2bf(acc[mi][ni][j]);
            }
}

// out-proj: C[M,N] f32 = A x B^T + aux (residual).
// BM=64 tiles -> 512 blocks = 2+/CU resident (256-block version was 1/CU: no
// co-resident partner to hide the vmcnt-drain stall). XCD swizzle, nwg=512.
#define OBM 64
__global__ __launch_bounds__(256)
void gemm_out_k(const ushort* __restrict__ A, const ushort* __restrict__ Bm,
                float* __restrict__ Cp, const float* __restrict__ aux){
    __shared__ __align__(16) ushort As[OBM * BK];
    __shared__ __align__(16) ushort Bs[BN * BK];
    const int wid9 = (blockIdx.x & 7) * 64 + (blockIdx.x >> 3);  // nwg=512, bijective
    const int col0 = (wid9 & 7) * BN;
    const int row0 = (wid9 >> 3) * OBM;
    const int tid = threadIdx.x;
    const int lane = tid & 63;
    const int wid = tid >> 6;
    const int wm = wid >> 1, wn = wid & 1;   // wave tile 32x64
    f32x4 acc[2][4] = {};
    const int l8 = lane >> 3;
    const int c8 = (lane & 7) * 8;

    for (int k0 = 0; k0 < E_; k0 += BK){
        #pragma unroll
        for (int i = 0; i < 2; ++i){
            const int R0 = wid * 16 + i * 8;
            gld16(A + (size_t)(row0 + R0 + l8) * E_ + k0 + c8, As + R0 * BK);
        }
        #pragma unroll
        for (int i = 0; i < 4; ++i){
            const int R0 = wid * 32 + i * 8;
            gld16(Bm + (size_t)(col0 + R0 + l8) * E_ + k0 + c8, Bs + R0 * BK);
        }
        __syncthreads();
        #pragma unroll
        for (int kk = 0; kk < 2; ++kk){
            bf16x8 af[2], bfr[4];
            const int krow = lane & 15;
            const int kcol = kk * 32 + (lane >> 4) * 8;
            #pragma unroll
            for (int mi = 0; mi < 2; ++mi)
                af[mi] = *(const bf16x8*)(As + (wm*32 + mi*16 + krow) * BK + kcol);
            #pragma unroll
            for (int ni = 0; ni < 4; ++ni)
                bfr[ni] = *(const bf16x8*)(Bs + (wn*64 + ni*16 + krow) * BK + kcol);
            #pragma unroll
            for (int mi = 0; mi < 2; ++mi)
                #pragma unroll
                for (int ni = 0; ni < 4; ++ni)
                    acc[mi][ni] = __builtin_amdgcn_mfma_f32_16x16x32_bf16(af[mi], bfr[ni], acc[mi][ni], 0, 0, 0);
        }
        __syncthreads();
    }
    #pragma unroll
    for (int mi = 0; mi < 2; ++mi)
        #pragma unroll
        for (int ni = 0; ni < 4; ++ni)
            #pragma unroll
            for (int j = 0; j < 4; ++j){
                int r = row0 + wm*32 + mi*16 + (lane >> 4) * 4 + j;
                int c = col0 + wn*64 + ni*16 + (lane & 15);
                size_t idx = (size_t)r * D_ + c;
                Cp[idx] = acc[mi][ni][j] + aux[idx];
            }
}

// ---------------- C96 GEMM, split-K: part[ks][4096][128] f32 partials ----------------
__global__ __launch_bounds__(256)
void gemm_c96_sk(const ushort* __restrict__ A, const ushort* __restrict__ Bm,
                 float* __restrict__ part){
    __shared__ __align__(16) ushort As[BM * BK];
    __shared__ __align__(16) ushort Bs[BN * BK];
    const int ks = blockIdx.x;
    const int row0 = blockIdx.y * BM;
    const int tid = threadIdx.x;
    const int lane = tid & 63;
    const int wid = tid >> 6;
    const int wm = wid >> 1, wn = wid & 1;
    f32x4 acc[4][4] = {};
    const int l8 = lane >> 3;
    const int c8 = (lane & 7) * 8;

    for (int k0 = ks * (E_ / KS_); k0 < (ks + 1) * (E_ / KS_); k0 += BK){
        #pragma unroll
        for (int i = 0; i < 4; ++i){
            const int R0 = wid * 32 + i * 8;
            gld16(A + (size_t)(row0 + R0 + l8) * E_ + k0 + c8, As + R0 * BK);
            gld16(Bm + (size_t)(R0 + l8) * E_ + k0 + c8, Bs + R0 * BK);
        }
        __syncthreads();
        #pragma unroll
        for (int kk = 0; kk < 2; ++kk){
            bf16x8 af[4], bfr[4];
            const int krow = lane & 15;
            const int kcol = kk * 32 + (lane >> 4) * 8;
            #pragma unroll
            for (int mi = 0; mi < 4; ++mi)
                af[mi] = *(const bf16x8*)(As + (wm*64 + mi*16 + krow) * BK + kcol);
            #pragma unroll
            for (int ni = 0; ni < 4; ++ni)
                bfr[ni] = *(const bf16x8*)(Bs + (wn*64 + ni*16 + krow) * BK + kcol);
            #pragma unroll
            for (int mi = 0; mi < 4; ++mi)
                #pragma unroll
                for (int ni = 0; ni < 4; ++ni)
                    acc[mi][ni] = __builtin_amdgcn_mfma_f32_16x16x32_bf16(af[mi], bfr[ni], acc[mi][ni], 0, 0, 0);
        }
        __syncthreads();
    }
    float* dst = part + (size_t)ks * M_ * 128;
    #pragma unroll
    for (int mi = 0; mi < 4; ++mi)
        #pragma unroll
        for (int ni = 0; ni < 4; ++ni)
            #pragma unroll
            for (int j = 0; j < 4; ++j){
                int r = row0 + wm*64 + mi*16 + (lane >> 4) * 4 + j;
                int c = wn*64 + ni*16 + (lane & 15);
                dst[(size_t)r * 128 + c] = acc[mi][ni][j];
            }
}

__global__ __launch_bounds__(256) void c96_reduce_k(const float* __restrict__ part,
                                                    ushort* __restrict__ C96){
    int i4 = blockIdx.x * 256 + threadIdx.x;     // over M_*128/4
    float4 a = *(const float4*)(part + (size_t)i4 * 4);
    #pragma unroll
    for (int k = 1; k < KS_; ++k){
        float4 b = *(const float4*)(part + (size_t)k * M_ * 128 + (size_t)i4 * 4);
        a.x += b.x; a.y += b.y; a.z += b.z; a.w += b.w;
    }
    ushort4 o;
    o.x = f2bf(a.x); o.y = f2bf(a.y); o.z = f2bf(a.z); o.w = f2bf(a.w);
    *(ushort4*)(C96 + (size_t)i4 * 4) = o;
}

// ---------------- causal depthwise conv1d + silu -> bf16 only ----------------
__global__ __launch_bounds__(256) void conv_silu_k(const ushort* __restrict__ xpre,
                                                   const float* __restrict__ conv_w,
                                                   const float* __restrict__ conv_b,
                                                   ushort* __restrict__ xb){
    int i4 = blockIdx.x * 256 + threadIdx.x;
    if (i4 >= M_ * E_ / 4) return;
    int idx = i4 * 4;
    int e = idx & (E_ - 1);
    int bl = idx >> 11;
    int t = bl & (L_ - 1);
    float acc[4];
    #pragma unroll
    for (int j = 0; j < 4; ++j) acc[j] = conv_b[e + j];
    #pragma unroll
    for (int k = 0; k < 4; ++k){
        int dt = 3 - k;
        if (t >= dt){
            ushort4 xv = *(const ushort4*)(xpre + idx - dt * E_);
            acc[0] += bf2f(xv.x) * conv_w[(e+0)*4 + k];
            acc[1] += bf2f(xv.y) * conv_w[(e+1)*4 + k];
            acc[2] += bf2f(xv.z) * conv_w[(e+2)*4 + k];
            acc[3] += bf2f(xv.w) * conv_w[(e+3)*4 + k];
        }
    }
    ushort4 sb;
    #pragma unroll
    for (int j = 0; j < 4; ++j){
        float s = acc[j] / (1.f + __expf(-acc[j]));
        ((ushort*)&sb)[j] = f2bf(s);
    }
    *(ushort4*)(xb + idx) = sb;
}

// ---------------- chunk-parallel selective scan, delta fused via MFMA ----------------
// CH=32 chunks: LDS ~20KB -> 8 blocks/CU, __launch_bounds__(256,8) (r11: occ 70%).
// XCD swizzle: give each XCD contiguous (s,b) panels so the 128 e-blocks sharing a
// C96 t-slice hit the same private L2 (cuts C96 re-fetch ~8x).
#define SF2 36   // f32 tile stride (144B, 16B-aligned)
#define SYD 20   // sy stride

__device__ __forceinline__ void seg_swz(int& b, int& s, int& e0){
    int lin = blockIdx.x + 128 * (blockIdx.y + 16 * blockIdx.z);   // nwg = 4096
    int swz = (lin & 7) * 512 + (lin >> 3);                        // bijective
    e0 = (swz & 127) * 16;
    s  = (swz >> 7) & 15;
    b  = swz >> 11;
}

// grid (E_/16, SSEG, B_), block 256 = 16 e x 16 n
__global__ __launch_bounds__(256, 8) void seg1_k(const ushort* __restrict__ xb,
                                              const ushort* __restrict__ C96,
                                              const ushort* __restrict__ wd2b,
                                              const float* __restrict__ wd2_bias,
                                              const float* __restrict__ A_log,
                                              float* __restrict__ F,
                                              float* __restrict__ segdt){
    int b, s, e0; seg_swz(b, s, e0);
    const int tid = threadIdx.x;
    const int lane = tid & 63, wid = tid >> 6;
    const int n = tid & 15, ei = tid >> 4;
    const int e = e0 + ei;
    const float Aen = -__expf(A_log[e * N_ + n]);
    float h = 0.f, sdt = 0.f;
    __shared__ __align__(16) ushort sxr[CH][72];
    __shared__ __align__(16) ushort swd2[16][72];
    __shared__ __align__(16) ushort sxu[16][40];
    __shared__ float sd[16][SF2], sdx[16][SF2], sB[16][SF2];
    const int tq = tid >> 3, qc = tid & 7;   // row 0..31, col-group 0..7

    if (tid < 128){
        int r = tid >> 3, cc = (tid & 7) * 8;
        *(uint4*)&swd2[r][cc] = *(const uint4*)(wd2b + (size_t)(e0 + r) * DR_ + cc);
    }
    const float bias = wd2_bias[e0 + (lane & 15)];

    for (int c = 0; c < LSEG / CH; ++c){
        int t0 = s * LSEG + c * CH;
        size_t row = (size_t)(b * L_ + t0 + tq);
        *(uint4*)&sxr[tq][qc * 8] = *(const uint4*)(C96 + row * 128 + qc * 8);
        ushort2 rB = *(const ushort2*)(C96 + row * 128 + 64 + qc * 2);
        ushort2 xu = *(const ushort2*)(xb + row * E_ + e0 + qc * 2);
        sB[qc*2+0][tq] = bf2f(rB.x); sB[qc*2+1][tq] = bf2f(rB.y);
        sxu[qc*2+0][tq] = xu.x; sxu[qc*2+1][tq] = xu.y;
        __syncthreads();
        // fused delta: waves 0,1 each compute one 16-t x 16-e tile
        if (wid < 2){
            f32x4 dacc = {};
            #pragma unroll
            for (int kk = 0; kk < 2; ++kk){
                bf16x8 af = *(const bf16x8*)&sxr[wid*16 + (lane & 15)][kk*32 + (lane >> 4)*8];
                bf16x8 bf = *(const bf16x8*)&swd2[lane & 15][kk*32 + (lane >> 4)*8];
                dacc = __builtin_amdgcn_mfma_f32_16x16x32_bf16(af, bf, dacc, 0, 0, 0);
            }
            const int crow = lane & 15;
            const int ttc = wid*16 + (lane >> 4)*4;
            float4 dv;
            dv.x = softplus_f(dacc[0] + bias);
            dv.y = softplus_f(dacc[1] + bias);
            dv.z = softplus_f(dacc[2] + bias);
            dv.w = softplus_f(dacc[3] + bias);
            *(float4*)&sd[crow][ttc] = dv;
            ushort4 xu4 = *(const ushort4*)&sxu[crow][ttc];
            float4 dxv;
            dxv.x = dv.x * bf2f(xu4.x); dxv.y = dv.y * bf2f(xu4.y);
            dxv.z = dv.z * bf2f(xu4.z); dxv.w = dv.w * bf2f(xu4.w);
            *(float4*)&sdx[crow][ttc] = dxv;
        }
        __syncthreads();
        #pragma unroll
        for (int t = 0; t < CH; t += 4){
            float4 d4  = *(const float4*)&sd[ei][t];
            float4 dx4 = *(const float4*)&sdx[ei][t];
            float4 b4  = *(const float4*)&sB[n][t];
            h = __expf(d4.x*Aen)*h + dx4.x*b4.x;
            h = __expf(d4.y*Aen)*h + dx4.y*b4.y;
            h = __expf(d4.z*Aen)*h + dx4.z*b4.z;
            h = __expf(d4.w*Aen)*h + dx4.w*b4.w;
            sdt += d4.x + d4.y + d4.z + d4.w;
        }
        __syncthreads();
    }
    size_t base = ((size_t)(b * SSEG + s) * E_ + e) * N_ + n;
    F[base] = h;
    if (n == 0) segdt[(size_t)(b * SSEG + s) * E_ + e] = sdt;
}

// sequential carry over SSEG segments per (b,e,n)
__global__ __launch_bounds__(256) void carry_k(const float* __restrict__ F,
                                               const float* __restrict__ segdt,
                                               const float* __restrict__ A_log,
                                               float* __restrict__ carr){
    int idx = blockIdx.x * 256 + threadIdx.x;
    int n = idx & 15;
    int e = (idx >> 4) & (E_ - 1);
    int b = idx >> 15;
    const float Aen = -__expf(A_log[e * N_ + n]);
    float c = 0.f;
    #pragma unroll
    for (int s = 0; s < SSEG; ++s){
        size_t base = ((size_t)(b * SSEG + s) * E_ + e) * N_ + n;
        carr[base] = c;
        float P = __expf(Aen * segdt[(size_t)(b * SSEG + s) * E_ + e]);
        c = P * c + F[base];
    }
}

// grid (E_/16, SSEG, B_), block 256; gate fused into store
__global__ __launch_bounds__(256, 8) void seg2_k(const ushort* __restrict__ xb,
                                              const ushort* __restrict__ C96,
                                              const ushort* __restrict__ wd2b,
                                              const float* __restrict__ wd2_bias,
                                              const float* __restrict__ A_log,
                                              const float* __restrict__ carr,
                                              const ushort* __restrict__ skipb,
                                              const float* __restrict__ W_D,
                                              ushort* __restrict__ y2){
    int b, s, e0; seg_swz(b, s, e0);
    const int tid = threadIdx.x;
    const int lane = tid & 63, wid = tid >> 6;
    const int n = tid & 15, ei = tid >> 4;
    const int e = e0 + ei;
    const float Aen = -__expf(A_log[e * N_ + n]);
    float h = carr[((size_t)(b * SSEG + s) * E_ + e) * N_ + n];
    __shared__ __align__(16) ushort sxr[CH][72];
    __shared__ __align__(16) ushort swd2[16][72];
    __shared__ __align__(16) ushort sxu[16][40];
    __shared__ float sd[16][SF2], sdx[16][SF2], sB[16][SF2], sC[16][SF2];
    __shared__ float sy[CH][SYD];
    const int tq = tid >> 3, qc = tid & 7;

    if (tid < 128){
        int r = tid >> 3, cc = (tid & 7) * 8;
        *(uint4*)&swd2[r][cc] = *(const uint4*)(wd2b + (size_t)(e0 + r) * DR_ + cc);
    }
    const float bias = wd2_bias[e0 + (lane & 15)];
    const float wv0 = W_D[e0 + qc * 2], wv1 = W_D[e0 + qc * 2 + 1];

    for (int c = 0; c < LSEG / CH; ++c){
        int t0 = s * LSEG + c * CH;
        size_t row = (size_t)(b * L_ + t0 + tq);
        *(uint4*)&sxr[tq][qc * 8] = *(const uint4*)(C96 + row * 128 + qc * 8);
        ushort2 rB = *(const ushort2*)(C96 + row * 128 + 64 + qc * 2);
        ushort2 rC = *(const ushort2*)(C96 + row * 128 + 80 + qc * 2);
        ushort2 xu = *(const ushort2*)(xb + row * E_ + e0 + qc * 2);
        sB[qc*2+0][tq] = bf2f(rB.x); sB[qc*2+1][tq] = bf2f(rB.y);
        sC[qc*2+0][tq] = bf2f(rC.x); sC[qc*2+1][tq] = bf2f(rC.y);
        sxu[qc*2+0][tq] = xu.x; sxu[qc*2+1][tq] = xu.y;
        __syncthreads();
        if (wid < 2){
            f32x4 dacc = {};
            #pragma unroll
            for (int kk = 0; kk < 2; ++kk){
                bf16x8 af = *(const bf16x8*)&sxr[wid*16 + (lane & 15)][kk*32 + (lane >> 4)*8];
                bf16x8 bf = *(const bf16x8*)&swd2[lane & 15][kk*32 + (lane >> 4)*8];
                dacc = __builtin_amdgcn_mfma_f32_16x16x32_bf16(af, bf, dacc, 0, 0, 0);
            }
            const int crow = lane & 15;
            const int ttc = wid*16 + (lane >> 4)*4;
            float4 dv;
            dv.x = softplus_f(dacc[0] + bias);
            dv.y = softplus_f(dacc[1] + bias);
            dv.z = softplus_f(dacc[2] + bias);
            dv.w = softplus_f(dacc[3] + bias);
            *(float4*)&sd[crow][ttc] = dv;
            ushort4 xu4 = *(const ushort4*)&sxu[crow][ttc];
            float4 dxv;
            dxv.x = dv.x * bf2f(xu4.x); dxv.y = dv.y * bf2f(xu4.y);
            dxv.z = dv.z * bf2f(xu4.z); dxv.w = dv.w * bf2f(xu4.w);
            *(float4*)&sdx[crow][ttc] = dxv;
        }
        __syncthreads();
        #pragma unroll
        for (int t = 0; t < CH; t += 4){
            float4 d4  = *(const float4*)&sd[ei][t];
            float4 dx4 = *(const float4*)&sdx[ei][t];
            float4 b4  = *(const float4*)&sB[n][t];
            float4 c4  = *(const float4*)&sC[n][t];
            float y0, y1, y2v, y3;
            h = __expf(d4.x*Aen)*h + dx4.x*b4.x;  y0 = h * c4.x;
            h = __expf(d4.y*Aen)*h + dx4.y*b4.y;  y1 = h * c4.y;
            h = __expf(d4.z*Aen)*h + dx4.z*b4.z;  y2v = h * c4.z;
            h = __expf(d4.w*Aen)*h + dx4.w*b4.w;  y3 = h * c4.w;
            // 4-value 16-lane butterfly reduce: 5 shfls
            float s01 = (n & 1) ? y0 : y1;
            float r01 = __shfl_xor(s01, 1);
            float s23 = (n & 1) ? y2v : y3;
            float r23 = __shfl_xor(s23, 1);
            float va, vb;
            if (n & 1){ va = y1 + r01; vb = y3 + r23; }
            else      { va = y0 + r01; vb = y2v + r23; }
            float s2 = (n & 2) ? va : vb;
            float r2 = __shfl_xor(s2, 2);
            float v = ((n & 2) ? vb : va) + r2;
            v += __shfl_xor(v, 4);
            v += __shfl_xor(v, 8);
            if (n < 4) sy[t + n][ei] = v;
        }
        __syncthreads();
        {
            // fused gate: y2 = (y + W_D*x) * silu(skip) -> bf16
            size_t orow = (size_t)(b * L_ + t0 + tq);
            float yv0 = sy[tq][qc*2], yv1 = sy[tq][qc*2+1];
            float xs0 = bf2f(sxu[qc*2+0][tq]), xs1 = bf2f(sxu[qc*2+1][tq]);
            ushort2 sv = *(const ushort2*)(skipb + orow * E_ + e0 + qc * 2);
            float sk0 = bf2f(sv.x), sk1 = bf2f(sv.y);
            ushort2 o;
            o.x = f2bf((yv0 + wv0 * xs0) * (sk0 / (1.f + __expf(-sk0))));
            o.y = f2bf((yv1 + wv1 * xs1) * (sk1 / (1.f + __expf(-sk1))));
            *(ushort2*)(y2 + orow * E_ + e0 + qc * 2) = o;
        }
        __syncthreads();
    }
}

// ---------------- launch ----------------
extern "C" void kernel_launch(void* const* d_in, const int* in_sizes, int n_in,
                              void* d_out, int out_size, void* d_ws, size_t ws_size,
                              hipStream_t stream){
    const float* resid  = (const float*)d_in[0];
    const float* norm_w = (const float*)d_in[1];
    const float* skip_w = (const float*)d_in[2];
    const float* in_w   = (const float*)d_in[3];
    const float* conv_w = (const float*)d_in[4];
    const float* conv_b = (const float*)d_in[5];
    const float* wd1    = (const float*)d_in[6];
    const float* wd2    = (const float*)d_in[7];
    const float* wd2_b  = (const float*)d_in[8];
    const float* wB     = (const float*)d_in[9];
    const float* wC     = (const float*)d_in[10];
    const float* A_log  = (const float*)d_in[11];
    const float* W_D    = (const float*)d_in[12];
    const float* out_w  = (const float*)d_in[13];
    float* out = (float*)d_out;

    char* ws = (char*)d_ws;
    size_t off = 0;
    auto alloc = [&](size_t bytes) -> char* {
        char* p = ws + off;
        off += (bytes + 255) & ~(size_t)255;
        return p;
    };
    // --- aliased region: wis (8MB) + xn (8MB) dead before the C96 GEMM runs;
    //     split-K partial buffer (16MB f32) reuses them.
    char* alias_base = ws;
    ushort* wis_b   = (ushort*)alloc((size_t)2 * E_ * D_ * 2);  // 8MB stacked [in_w; skip_w]
    ushort* xn_b    = (ushort*)alloc((size_t)M_ * D_ * 2);      // 8MB
    ushort* xpre_b  = (ushort*)alloc((size_t)M_ * E_ * 2);      // 16MB
    float*  part_buf= (float*)alias_base;                       // 16MB alias (KS_*M_*128*4)
    // --- persistent buffers
    ushort* wo_b    = (ushort*)alloc((size_t)D_ * E_ * 2);       // 4MB
    ushort* wd2_bf  = (ushort*)alloc((size_t)E_ * DR_ * 2);      // 256KB
    ushort* W96_b   = (ushort*)alloc((size_t)128 * E_ * 2);      // 512KB
    ushort* skip_b  = (ushort*)alloc((size_t)M_ * E_ * 2);       // 16MB
    ushort* xb_b    = (ushort*)alloc((size_t)M_ * E_ * 2);       // 16MB
    ushort* C96_b   = (ushort*)alloc((size_t)M_ * 128 * 2);      // 1MB
    float*  scr     = (float*)alloc((size_t)9 * 1024 * 1024);    // 9MB scratch
    ushort* y2_b    = (ushort*)alloc((size_t)M_ * E_ * 2);       // 16MB
    // sub-layout of scr: F (4MB) | carr (4MB) | segdt (256KB)
    float* F_buf    = scr;
    float* carr_buf = scr + (size_t)B_ * SSEG * E_ * N_;
    float* segdt_buf= scr + (size_t)2 * B_ * SSEG * E_ * N_;
    (void)ws_size; (void)in_sizes; (void)n_in; (void)out_size;

    const int thr = 256;

    // fused weight prep (replaces 7 cvt + zero launches)
    prep_k<<<(PR7 + 255)/256, thr, 0, stream>>>(in_w, skip_w, out_w, wd2, wd1, wB, wC,
                                                wis_b, wo_b, wd2_bf, W96_b);

    // RMSNorm
    rmsnorm_k<<<M_, thr, 0, stream>>>(resid, norm_w, xn_b);

    // fused in-proj + skip-proj: [4096,4096] = [4096,1024] x [4096,1024]^T
    gemm_dual_k<<<1024, thr, 0, stream>>>(xn_b, wis_b, xpre_b, skip_b);

    // conv + silu -> bf16
    conv_silu_k<<<(M_*E_/4 + 255)/256, thr, 0, stream>>>(xpre_b, conv_w, conv_b, xb_b);

    // C96[4096,128] = x[4096,2048] x W96[128,2048]^T, split-K x8 + reduce
    gemm_c96_sk<<<dim3(KS_, M_/BM), thr, 0, stream>>>(xb_b, W96_b, part_buf);
    c96_reduce_k<<<(M_*128/4)/256, thr, 0, stream>>>(part_buf, C96_b);

    // chunk-parallel selective scan with fused delta; gate fused into seg2
    seg1_k<<<dim3(E_/16, SSEG, B_), thr, 0, stream>>>(xb_b, C96_b, wd2_bf, wd2_b, A_log, F_buf, segdt_buf);
    carry_k<<<(B_*E_*N_)/256, thr, 0, stream>>>(F_buf, segdt_buf, A_log, carr_buf);
    seg2_k<<<dim3(E_/16, SSEG, B_), thr, 0, stream>>>(xb_b, C96_b, wd2_bf, wd2_b, A_log, carr_buf,
                                                      skip_b, W_D, y2_b);

    // out-proj + residual: out[4096,1024] = y2[4096,2048] x out_w[1024,2048]^T + resid
    gemm_out_k<<<512, thr, 0, stream>>>(y2_b, wo_b, out, resid);
}